// Round 6
// baseline (9766.821 us; speedup 1.0000x reference)
//
// BiLSTM tagger — MI355X. Round 6: fence-free scan (bypass h loads).
// Change log vs R5: k_scan no longer issues ANY cache-invalidating fence.
// h consume switched to relaxed agent-scope atomic u64 loads (sc0 sc1 ->
// read MALL coherence point directly), matching the write-through publish.
// Flag handshake alone gives causality. L1/L2 stay warm across all 256 steps
// (weights/pre/spills now hit cache; R1-R5 re-fetched them from L3 after each
// per-step full L2 invalidate — the invariant ~9us/step floor). h loads are
// 2-deep pipelined over batch-tiles with named A0/A1 buffers (static idx).
#include <hip/hip_runtime.h>

typedef unsigned short u16;
typedef unsigned long long ull;
typedef short short8 __attribute__((ext_vector_type(8)));
typedef float float4_ __attribute__((ext_vector_type(4)));
typedef short8 short8a __attribute__((may_alias));
typedef float4_ float4a __attribute__((may_alias));
typedef ull ulla __attribute__((may_alias));

#define MFMA16(a, b, c) __builtin_amdgcn_mfma_f32_16x16x32_bf16((a), (b), (c), 0, 0, 0)

static __device__ __forceinline__ float b2f(u16 v) { return __uint_as_float(((unsigned)v) << 16); }
static __device__ __forceinline__ u16 f2b(float f) {
  unsigned x = __float_as_uint(f);
  return (u16)((x + 0x7fffu + ((x >> 16) & 1u)) >> 16);
}
static __device__ __forceinline__ float ldv(const void* p, long long i, int isbf) {
  return isbf ? b2f(((const u16*)p)[i]) : ((const float*)p)[i];
}
static __device__ __forceinline__ float sigm(float x) { return 1.f / (1.f + __expf(-x)); }
static __device__ __forceinline__ float tanh_(float x) { return 1.f - 2.f / (__expf(2.f * x) + 1.f); }
static __device__ __forceinline__ float4_ splat4(float v) { float4_ r; r[0]=v; r[1]=v; r[2]=v; r[3]=v; return r; }

// bypass (device-coherent) 16B fragment load: two relaxed agent atomic u64s
static __device__ __forceinline__ short8 ldh(const u16* p) {
  struct P { ull a, b; } t;
  t.a = __hip_atomic_load((const ull*)(const void*)p, __ATOMIC_RELAXED, __HIP_MEMORY_SCOPE_AGENT);
  t.b = __hip_atomic_load((const ull*)(const void*)p + 1, __ATOMIC_RELAXED, __HIP_MEMORY_SCOPE_AGENT);
  return __builtin_bit_cast(short8, t);
}

// ---------------- dtype detection (f32 vs bf16 input buffers) ----------------
__global__ __launch_bounds__(256) void k_detect(const unsigned* __restrict__ wtag, int* __restrict__ flag) {
  __shared__ int cs;
  if (threadIdx.x == 0) cs = 0;
  __syncthreads();
  int hits = 0;
  for (int i = threadIdx.x; i < 1024; i += 256) {
    unsigned b = (wtag[i] >> 8) & 0x7fu;
    hits += (b >= 0x36u && b <= 0x3fu) ? 1 : 0;
  }
  atomicAdd(&cs, hits);
  __syncthreads();
  if (threadIdx.x == 0) *flag = (cs > 512) ? 1 : 0;
}

// ---------------- weight conversion to bf16 workspace (x8 vectorized) ----------------
struct WSegs { const void* src[15]; int dst[15]; int n[15]; };
__global__ __launch_bounds__(256) void k_convw(WSegs s, u16* __restrict__ wt, const int* __restrict__ flagp) {
  const int isbf = *flagp;
  const long long total8 = 9830400 / 8;
  for (long long i8 = (long long)blockIdx.x * 256 + threadIdx.x; i8 < total8; i8 += (long long)gridDim.x * 256) {
    const long long i = i8 * 8;
    int k = 0;
#pragma unroll
    for (int j = 1; j < 15; ++j) if (i >= (long long)s.dst[j]) k = j;
    const long long loc = i - s.dst[k];
    short8 out;
    if (!s.src[k]) {
      for (int j = 0; j < 8; ++j) out[j] = 0;
    } else if (isbf) {
      out = *(const short8a*)((const u16*)s.src[k] + loc);
    } else {
      const float* fp = (const float*)s.src[k] + loc;
      const float4_ f0 = *(const float4a*)fp;
      const float4_ f1 = *(const float4a*)(fp + 4);
#pragma unroll
      for (int j = 0; j < 4; ++j) { out[j] = (short)f2b(f0[j]); out[j + 4] = (short)f2b(f1[j]); }
    }
    *(short8a*)(wt + i) = out;
  }
}

struct BSegs { const void* a[8]; const void* b[8]; int dst[8]; int n[8]; int np[8]; };
__global__ __launch_bounds__(256) void k_convb(BSegs s, float* __restrict__ bias, const int* __restrict__ flagp) {
  const int isbf = *flagp;
  for (int i = blockIdx.x * 256 + threadIdx.x; i < 9536; i += gridDim.x * 256) {
    int k = 0;
#pragma unroll
    for (int j = 1; j < 8; ++j) if (i >= s.dst[j]) k = j;
    const int loc = i - s.dst[k];
    float v = 0.f;
    if (loc < s.n[k]) {
      v = ldv(s.a[k], loc, isbf);
      if (s.b[k]) v += ldv(s.b[k], loc, isbf);
    }
    bias[i] = v;
  }
}

// ---------------- word embedding gather into cat[:,0:256] ----------------
__global__ __launch_bounds__(128) void k_wordgather(const int* __restrict__ sent, const void* __restrict__ wemb,
                                                    u16* __restrict__ cat, const int* __restrict__ flagp) {
  const int n = blockIdx.x;
  const int idx = sent[n];
  const int isbf = *flagp;
  for (int d = threadIdx.x; d < 256; d += 128)
    cat[(long long)n * 512 + d] = f2b(ldv(wemb, (long long)idx * 256 + d, isbf));
}

// ---------------- char biLSTM: 64 seqs/block, 16 steps, D=64 H=128 ----------------
__global__ __launch_bounds__(256) void k_char(const int* __restrict__ cs, const void* __restrict__ wchar,
                                              const u16* __restrict__ wihF, const u16* __restrict__ whhF,
                                              const u16* __restrict__ wihB, const u16* __restrict__ whhB,
                                              const float* __restrict__ biasF, const float* __restrict__ biasB,
                                              u16* __restrict__ cat, const int* __restrict__ flagp) {
  const int dir = blockIdx.y;
  const int nb = blockIdx.x;
  const u16* wih = dir ? wihB : wihF;
  const u16* whh = dir ? whhB : whhF;
  const float* bias = dir ? biasB : biasF;
  const int isbf = *flagp;
  __shared__ __align__(16) u16 xs[64][72];
  __shared__ __align__(16) u16 hs[64][136];
  const int tid = threadIdx.x, wv = tid >> 6, lane = tid & 63;
  for (int i = tid; i < 64 * 136; i += 256) ((u16*)hs)[i] = 0;
  float c[2][4][4];
#pragma unroll
  for (int a1 = 0; a1 < 2; ++a1)
#pragma unroll
    for (int a2 = 0; a2 < 4; ++a2)
#pragma unroll
      for (int a3 = 0; a3 < 4; ++a3) c[a1][a2][a3] = 0.f;

  for (int tt = 0; tt < 16; ++tt) {
    const int t = dir ? (15 - tt) : tt;
    {
      const int sid = tid >> 2, part = tid & 3;
      const int n = nb * 64 + sid;
      const int idx = cs[n * 16 + t];
#pragma unroll
      for (int q = 0; q < 16; ++q) {
        const int d2 = part * 16 + q;
        float v = 0.f;
        if (idx != 0) v = ldv(wchar, (long long)idx * 64 + d2, isbf);
        xs[sid][d2] = f2b(v);
      }
    }
    __syncthreads();
    float4_ acc[2][4][4];
#pragma unroll
    for (int ut = 0; ut < 2; ++ut)
#pragma unroll
      for (int g = 0; g < 4; ++g) {
        const float bv = bias[g * 128 + (wv + 4 * ut) * 16 + (lane & 15)];
#pragma unroll
        for (int rt = 0; rt < 4; ++rt) acc[ut][g][rt] = splat4(bv);
      }
#pragma unroll
    for (int kc = 0; kc < 6; ++kc) {
      short8 a[4];
      if (kc < 2) {
#pragma unroll
        for (int rt = 0; rt < 4; ++rt)
          a[rt] = *(const short8a*)&xs[rt * 16 + (lane & 15)][kc * 32 + (lane >> 4) * 8];
      } else {
#pragma unroll
        for (int rt = 0; rt < 4; ++rt)
          a[rt] = *(const short8a*)&hs[rt * 16 + (lane & 15)][(kc - 2) * 32 + (lane >> 4) * 8];
      }
#pragma unroll
      for (int ut = 0; ut < 2; ++ut)
#pragma unroll
        for (int g = 0; g < 4; ++g) {
          const int col = g * 128 + (wv + 4 * ut) * 16 + (lane & 15);
          short8 bfr;
          if (kc < 2) bfr = *(const short8a*)(wih + col * 64 + kc * 32 + (lane >> 4) * 8);
          else        bfr = *(const short8a*)(whh + col * 128 + (kc - 2) * 32 + (lane >> 4) * 8);
#pragma unroll
          for (int rt = 0; rt < 4; ++rt) acc[ut][g][rt] = MFMA16(a[rt], bfr, acc[ut][g][rt]);
        }
    }
    __syncthreads();
#pragma unroll
    for (int ut = 0; ut < 2; ++ut)
#pragma unroll
      for (int rt = 0; rt < 4; ++rt)
#pragma unroll
        for (int r = 0; r < 4; ++r) {
          const float iv = acc[ut][0][rt][r];
          const float fv = acc[ut][1][rt][r];
          const float gv = acc[ut][2][rt][r];
          const float ov = acc[ut][3][rt][r];
          float& cc = c[ut][rt][r];
          cc = sigm(fv) * cc + sigm(iv) * tanh_(gv);
          const float h = sigm(ov) * tanh_(cc);
          const int seq = rt * 16 + (lane >> 4) * 4 + r;
          const int u = (wv + 4 * ut) * 16 + (lane & 15);
          const u16 hv = f2b(h);
          hs[seq][u] = hv;
          if (tt == 15) cat[(long long)(nb * 64 + seq) * 512 + 256 + dir * 128 + u] = hv;
        }
  }
}

// ---------------- generic MFMA GEMM ----------------
template <int TM, int TN, int PERM, int OUTM>
__global__ __launch_bounds__(256) void k_gemm(const u16* __restrict__ A, const u16* __restrict__ Wt,
                                              const float* __restrict__ bias, void* __restrict__ Cout,
                                              const int N, const int K, const int ldc,
                                              const int* __restrict__ flagp) {
  constexpr int RT = TM / 16;
  constexpr int CPW = TN / 64;
  const int bm = blockIdx.x, bn = blockIdx.y;
  const int tid = threadIdx.x, wv = tid >> 6, lane = tid & 63;
  __shared__ __align__(16) u16 As[TM][72];
  float4_ acc[CPW][RT];
#pragma unroll
  for (int ci = 0; ci < CPW; ++ci)
#pragma unroll
    for (int rt = 0; rt < RT; ++rt) acc[ci][rt] = splat4(0.f);
  const int nk = K >> 6;
  for (int kc = 0; kc < nk; ++kc) {
    __syncthreads();
    for (int idx = tid; idx < TM * 4; idx += 256) {
      const int r = idx >> 2, sg = idx & 3;
      const u16* src = A + (long long)(bm * TM + r) * K + kc * 64 + sg * 16;
      *(short8a*)&As[r][sg * 16] = *(const short8a*)src;
      *(short8a*)&As[r][sg * 16 + 8] = *(const short8a*)(src + 8);
    }
    __syncthreads();
#pragma unroll
    for (int kk = 0; kk < 2; ++kk) {
      short8 af[RT];
#pragma unroll
      for (int rt = 0; rt < RT; ++rt)
        af[rt] = *(const short8a*)&As[rt * 16 + (lane & 15)][kk * 32 + (lane >> 4) * 8];
#pragma unroll
      for (int ci = 0; ci < CPW; ++ci) {
        const int ct = wv + ci * 4;
        const short8 bf = *(const short8a*)(Wt + (long long)(bn * TN + ct * 16 + (lane & 15)) * K +
                                            kc * 64 + kk * 32 + (lane >> 4) * 8);
#pragma unroll
        for (int rt = 0; rt < RT; ++rt) acc[ci][rt] = MFMA16(af[rt], bf, acc[ci][rt]);
      }
    }
  }
  const int isbf = (OUTM == 1) ? *flagp : 0;
#pragma unroll
  for (int ci = 0; ci < CPW; ++ci)
#pragma unroll
    for (int rt = 0; rt < RT; ++rt)
#pragma unroll
      for (int r = 0; r < 4; ++r) {
        const int row = bm * TM + rt * 16 + (lane >> 4) * 4 + r;
        const int col = bn * TN + (wv + ci * 4) * 16 + (lane & 15);
        if (col < N) {
          const float v = acc[ci][rt][r] + bias[col];
          long long orow;
          if (PERM == 0) orow = row;
          else if (PERM == 1) orow = (long long)(row & 255) * 64 + (row >> 8);
          else orow = (long long)(row & 63) * 256 + (row >> 6);
          if (OUTM == 0) ((u16*)Cout)[orow * ldc + col] = f2b(v);
          else if (isbf) ((u16*)Cout)[orow * ldc + col] = f2b(v);
          else ((float*)Cout)[orow * ldc + col] = v;
        }
      }
}

// ---------------- persistent LSTM scan (one layer, both dirs) ----------------
// grid (16, 2=dir). Block owns 32 hidden units. Wave w owns GATE w. h exchange
// entirely at the MALL coherence point: write-through atomic stores (publish)
// + relaxed agent atomic loads (consume, bypass L1/L2). NO fences/invalidates
// -> weights, pre, spills stay cache-warm across all 256 steps. h loads
// 2-deep pipelined over batch-tiles (A0/A1 named buffers, static indexing).
__global__ __launch_bounds__(256, 1) void k_scan(const u16* __restrict__ pre0, const u16* __restrict__ pre1,
                                                 const u16* __restrict__ whh0, const u16* __restrict__ whh1,
                                                 u16* __restrict__ o_out, u16* __restrict__ hbuf,
                                                 int* __restrict__ flags) {
  const int dir = blockIdx.y, blk = blockIdx.x;
  const u16* __restrict__ pre = dir ? pre1 : pre0;
  const u16* __restrict__ whh = dir ? whh1 : whh0;
  u16* hb = hbuf + dir * (2 * 64 * 512);
  int* myflags = flags + dir * 16;
  const int u0 = blk * 32;
  __shared__ __align__(16) float xch[64 * 128];  // 32KB, byte-addressed XOR swizzle
  const int tid = threadIdx.x, wv = tid >> 6, lane = tid & 63;
  const int l15 = lane & 15, q = lane >> 4;

  // weight fragments: gate = wv, unit-tile ci, rows u0+ci*16+l15.
  // (reloads, if the compiler sinks them, now hit warm L1/L2 every step.)
  short8 sw[2][16];
#pragma unroll
  for (int ci = 0; ci < 2; ++ci)
#pragma unroll
    for (int kc = 0; kc < 16; ++kc)
      sw[ci][kc] = *(const short8a*)(whh + (long long)(wv * 512 + u0 + ci * 16 + l15) * 512 + kc * 32 + q * 8);

  // activation ownership: batch ab, unit octet u0+au .. +8
  const int ab = tid >> 2;
  const int au = (tid & 3) * 8;
  float c8[8];
#pragma unroll
  for (int j = 0; j < 8; ++j) c8[j] = 0.f;

  short8 pr[4], prn[4];
  {
    const int t0 = dir ? 255 : 0;
    const u16* pb = pre + (long long)(t0 * 64 + ab) * 2048 + u0 + au;
#pragma unroll
    for (int g = 0; g < 4; ++g) pr[g] = *(const short8a*)(pb + g * 512);
  }

  for (int tt = 0; tt < 256; ++tt) {
    const int t = dir ? (255 - tt) : tt;
    const u16* hrd = hb + (tt & 1) * 32768;
    u16* hwr = hb + ((tt + 1) & 1) * 32768;

    const u16* hl0 = hrd + l15 * 512 + q * 8;
    const u16* hl1 = hl0 + 16 * 512;
    const u16* hl2 = hl0 + 32 * 512;
    const u16* hl3 = hl0 + 48 * 512;

    // 2-deep pipelined bypass loads over the 4 batch-tiles
    short8 A0[16], A1[16];
#pragma unroll
    for (int kc = 0; kc < 16; ++kc) A0[kc] = ldh(hl0 + kc * 32);
#pragma unroll
    for (int kc = 0; kc < 16; ++kc) A1[kc] = ldh(hl1 + kc * 32);

    float4_ acc[2][4];
#pragma unroll
    for (int ci = 0; ci < 2; ++ci)
#pragma unroll
      for (int bt = 0; bt < 4; ++bt) acc[ci][bt] = splat4(0.f);

#pragma unroll
    for (int kc = 0; kc < 16; ++kc) {
      acc[0][0] = MFMA16(sw[0][kc], A0[kc], acc[0][0]);
      acc[1][0] = MFMA16(sw[1][kc], A0[kc], acc[1][0]);
    }
#pragma unroll
    for (int kc = 0; kc < 16; ++kc) A0[kc] = ldh(hl2 + kc * 32);
#pragma unroll
    for (int kc = 0; kc < 16; ++kc) {
      acc[0][1] = MFMA16(sw[0][kc], A1[kc], acc[0][1]);
      acc[1][1] = MFMA16(sw[1][kc], A1[kc], acc[1][1]);
    }
#pragma unroll
    for (int kc = 0; kc < 16; ++kc) A1[kc] = ldh(hl3 + kc * 32);
#pragma unroll
    for (int kc = 0; kc < 16; ++kc) {
      acc[0][2] = MFMA16(sw[0][kc], A0[kc], acc[0][2]);
      acc[1][2] = MFMA16(sw[1][kc], A0[kc], acc[1][2]);
    }
#pragma unroll
    for (int kc = 0; kc < 16; ++kc) {
      acc[0][3] = MFMA16(sw[0][kc], A1[kc], acc[0][3]);
      acc[1][3] = MFMA16(sw[1][kc], A1[kc], acc[1][3]);
    }

    // gate exchange: swizzle ^((row&7)<<4) -> conflict-light b128
#pragma unroll
    for (int ci = 0; ci < 2; ++ci)
#pragma unroll
      for (int bt = 0; bt < 4; ++bt) {
        const int b = bt * 16 + l15;
        const int lrb = wv * 32 + ci * 16 + q * 4;
        *(float4a*)((char*)xch + b * 512 + ((lrb * 4) ^ ((b & 7) << 4))) = acc[ci][bt];
      }
    __syncthreads();
    float4_ gv[4][2];
#pragma unroll
    for (int g = 0; g < 4; ++g)
#pragma unroll
      for (int h2 = 0; h2 < 2; ++h2) {
        const int lr = g * 32 + au + h2 * 4;
        gv[g][h2] = *(const float4a*)((const char*)xch + ab * 512 + ((lr * 4) ^ ((ab & 7) << 4)));
      }
    ull hv[2]; hv[0] = 0; hv[1] = 0;
#pragma unroll
    for (int j = 0; j < 8; ++j) {
      const float iv = gv[0][j >> 2][j & 3] + b2f((u16)pr[0][j]);
      const float fv = gv[1][j >> 2][j & 3] + b2f((u16)pr[1][j]);
      const float gg = gv[2][j >> 2][j & 3] + b2f((u16)pr[2][j]);
      const float ov = gv[3][j >> 2][j & 3] + b2f((u16)pr[3][j]);
      c8[j] = sigm(fv) * c8[j] + sigm(iv) * tanh_(gg);
      const float h = sigm(ov) * tanh_(c8[j]);
      hv[j >> 2] |= (ull)f2b(h) << (16 * (j & 3));
    }
#pragma unroll
    for (int p = 0; p < 2; ++p)
      __hip_atomic_store((ull*)(hwr + ab * 512 + u0 + au) + p, hv[p],
                         __ATOMIC_RELAXED, __HIP_MEMORY_SCOPE_AGENT);
    asm volatile("s_waitcnt vmcnt(0)" ::: "memory");  // h at coherent point
    __syncthreads();
    if (tid == 0)
      __hip_atomic_store(&myflags[blk], tt + 1, __ATOMIC_RELAXED, __HIP_MEMORY_SCOPE_AGENT);
    // overlap the wait: o_out store + next-step pre prefetch
    {
      ull* op = (ull*)(o_out + (long long)(t * 64 + ab) * 1024 + dir * 512 + u0 + au);
      op[0] = hv[0]; op[1] = hv[1];
    }
    {
      const int ttn = (tt < 255) ? tt + 1 : tt;
      const int tn = dir ? (255 - ttn) : ttn;
      const u16* pb = pre + (long long)(tn * 64 + ab) * 2048 + u0 + au;
#pragma unroll
      for (int g = 0; g < 4; ++g) prn[g] = *(const short8a*)(pb + g * 512);
    }
    if (tt != 255) {
      if (wv == 0) {
        int v = __hip_atomic_load(&myflags[l15], __ATOMIC_RELAXED, __HIP_MEMORY_SCOPE_AGENT);
        while (__all(v >= tt + 1) == 0) {
          __builtin_amdgcn_s_sleep(1);
          v = __hip_atomic_load(&myflags[l15], __ATOMIC_RELAXED, __HIP_MEMORY_SCOPE_AGENT);
        }
      }
      __syncthreads();                       // releases block; orders h loads after poll
      asm volatile("" ::: "memory");          // compiler barrier only — NO cache inv
    }
#pragma unroll
    for (int g = 0; g < 4; ++g) pr[g] = prn[g];
  }
}

// ---------------- launcher ----------------
static constexpr long long OFF_WT = 0;
static constexpr long long OFF_BIAS = 19660800;
static constexpr long long OFF_CAT = 19698944;
static constexpr long long OFF_EMB = 36476160;
static constexpr long long OFF_PRE = 44864768;
static constexpr long long OFF_O1 = 179082496;
static constexpr long long OFF_O2 = 212636928;
static constexpr long long OFF_SYNC = 246191360;
static constexpr long long SYNC_BYTES = 4096 + 524288;
static constexpr long long OFF_FLAG = OFF_SYNC + SYNC_BYTES;

extern "C" void kernel_launch(void* const* d_in, const int* in_sizes, int n_in,
                              void* d_out, int out_size, void* d_ws, size_t ws_size,
                              hipStream_t stream) {
  char* ws = (char*)d_ws;
  u16* wt = (u16*)(ws + OFF_WT);
  float* biasp = (float*)(ws + OFF_BIAS);
  u16* cat = (u16*)(ws + OFF_CAT);
  u16* emb = (u16*)(ws + OFF_EMB);
  u16* pre0 = (u16*)(ws + OFF_PRE);
  u16* pre1 = pre0 + (long long)16384 * 2048;
  u16* o1 = (u16*)(ws + OFF_O1);
  u16* o2 = (u16*)(ws + OFF_O2);
  int* cnt1 = (int*)(ws + OFF_SYNC);
  int* cnt2 = cnt1 + 512;
  u16* h1 = (u16*)(ws + OFF_SYNC + 4096);
  u16* h2 = h1 + 131072;
  int* flag = (int*)(ws + OFF_FLAG);

  hipMemsetAsync(ws + OFF_SYNC, 0, SYNC_BYTES, stream);
  k_detect<<<1, 256, 0, stream>>>((const unsigned*)d_in[30], flag);

  WSegs wsg;
  const int widx[14] = {4, 5, 8, 9, 12, 13, 16, 17, 20, 21, 24, 25, 28, 30};
  const int wdst[15] = {0, 32768, 98304, 131072, 196608, 720896, 1769472, 2293760,
                        3342336, 5439488, 6488064, 8585216, 9633792, 9764864, 9816064};
  const int wn[15] = {32768, 65536, 32768, 65536, 524288, 1048576, 524288, 1048576,
                      2097152, 1048576, 2097152, 1048576, 131072, 51200, 14336};
  for (int j = 0; j < 14; ++j) { wsg.src[j] = d_in[widx[j]]; wsg.dst[j] = wdst[j]; wsg.n[j] = wn[j]; }
  wsg.src[14] = nullptr; wsg.dst[14] = wdst[14]; wsg.n[14] = wn[14];
  k_convw<<<1200, 256, 0, stream>>>(wsg, wt, flag);

  BSegs bsg;
  const int ba[8] = {6, 10, 14, 18, 22, 26, 29, 31};
  const int bb[8] = {7, 11, 15, 19, 23, 27, -1, -1};
  const int bdst[8] = {0, 512, 1024, 3072, 5120, 7168, 9216, 9472};
  const int bn_[8] = {512, 512, 2048, 2048, 2048, 2048, 256, 50};
  const int bnp[8] = {512, 512, 2048, 2048, 2048, 2048, 256, 64};
  for (int j = 0; j < 8; ++j) {
    bsg.a[j] = d_in[ba[j]];
    bsg.b[j] = (bb[j] >= 0) ? d_in[bb[j]] : nullptr;
    bsg.dst[j] = bdst[j]; bsg.n[j] = bn_[j]; bsg.np[j] = bnp[j];
  }
  k_convb<<<40, 256, 0, stream>>>(bsg, biasp, flag);

  k_wordgather<<<16384, 128, 0, stream>>>((const int*)d_in[0], d_in[2], cat, flag);
  k_char<<<dim3(256, 2), 256, 0, stream>>>((const int*)d_in[1], d_in[3],
                                           wt + 0, wt + 32768, wt + 98304, wt + 131072,
                                           biasp + 0, biasp + 512, cat, flag);
  k_gemm<64, 64, 1, 0><<<dim3(256, 4), 256, 0, stream>>>(cat, wt + 9633792, biasp + 9216, emb, 256, 512, 256, flag);
  k_gemm<128, 256, 0, 0><<<dim3(128, 8), 256, 0, stream>>>(emb, wt + 196608, biasp + 1024, pre0, 2048, 256, 2048, flag);
  k_gemm<128, 256, 0, 0><<<dim3(128, 8), 256, 0, stream>>>(emb, wt + 1769472, biasp + 3072, pre1, 2048, 256, 2048, flag);
  k_scan<<<dim3(16, 2), 256, 0, stream>>>(pre0, pre1, wt + 720896, wt + 2293760, o1, h1, cnt1);
  k_gemm<128, 256, 0, 0><<<dim3(128, 8), 256, 0, stream>>>(o1, wt + 3342336, biasp + 5120, pre0, 2048, 1024, 2048, flag);
  k_gemm<128, 256, 0, 0><<<dim3(128, 8), 256, 0, stream>>>(o1, wt + 6488064, biasp + 7168, pre1, 2048, 1024, 2048, flag);
  k_scan<<<dim3(16, 2), 256, 0, stream>>>(pre0, pre1, wt + 5439488, wt + 8585216, o2, h2, cnt2);
  k_gemm<64, 64, 2, 1><<<dim3(256, 1), 256, 0, stream>>>(o2, wt + 9764864, biasp + 9472, d_out, 50, 1024, 50, flag);
}

// Round 7
// 5782.235 us; speedup vs baseline: 1.6891x; 1.6891x over previous
//
// BiLSTM tagger — MI355X. Round 7: k_scan rebuilt around per-step byte budget.
// Evidence R1-R6: step cost ≈ bytes re-moved into CU per step (fence refetch /
// redundant per-wave h reads / bypass fragment loads all ~equally bad).
// R7: (a) weights 64 VGPR/lane (8 waves x (gate,K-half)), loop-carried asm pin
// so remat is illegal; (b) h staged ONCE per block: 64KB cooperative bypass
// loads -> XOR-swizzled LDS, waves read only their 32KB; (c) no fences at all
// (R6-proven bypass store/load pairing, only for h+flags); (d) gate partial
// exchange via padded LDS, 1 thread = 4 outputs.
#include <hip/hip_runtime.h>

typedef unsigned short u16;
typedef unsigned long long ull;
typedef short short8 __attribute__((ext_vector_type(8)));
typedef float float4_ __attribute__((ext_vector_type(4)));
typedef short8 short8a __attribute__((may_alias));
typedef float4_ float4a __attribute__((may_alias));
typedef ull ulla __attribute__((may_alias));

#define MFMA16(a, b, c) __builtin_amdgcn_mfma_f32_16x16x32_bf16((a), (b), (c), 0, 0, 0)

static __device__ __forceinline__ float b2f(u16 v) { return __uint_as_float(((unsigned)v) << 16); }
static __device__ __forceinline__ u16 f2b(float f) {
  unsigned x = __float_as_uint(f);
  return (u16)((x + 0x7fffu + ((x >> 16) & 1u)) >> 16);
}
static __device__ __forceinline__ float ldv(const void* p, long long i, int isbf) {
  return isbf ? b2f(((const u16*)p)[i]) : ((const float*)p)[i];
}
static __device__ __forceinline__ float sigm(float x) { return 1.f / (1.f + __expf(-x)); }
static __device__ __forceinline__ float tanh_(float x) { return 1.f - 2.f / (__expf(2.f * x) + 1.f); }
static __device__ __forceinline__ float4_ splat4(float v) { float4_ r; r[0]=v; r[1]=v; r[2]=v; r[3]=v; return r; }

// ---------------- dtype detection (f32 vs bf16 input buffers) ----------------
__global__ __launch_bounds__(256) void k_detect(const unsigned* __restrict__ wtag, int* __restrict__ flag) {
  __shared__ int cs;
  if (threadIdx.x == 0) cs = 0;
  __syncthreads();
  int hits = 0;
  for (int i = threadIdx.x; i < 1024; i += 256) {
    unsigned b = (wtag[i] >> 8) & 0x7fu;
    hits += (b >= 0x36u && b <= 0x3fu) ? 1 : 0;
  }
  atomicAdd(&cs, hits);
  __syncthreads();
  if (threadIdx.x == 0) *flag = (cs > 512) ? 1 : 0;
}

// ---------------- weight conversion to bf16 workspace (x8 vectorized) ----------------
struct WSegs { const void* src[15]; int dst[15]; int n[15]; };
__global__ __launch_bounds__(256) void k_convw(WSegs s, u16* __restrict__ wt, const int* __restrict__ flagp) {
  const int isbf = *flagp;
  const long long total8 = 9830400 / 8;
  for (long long i8 = (long long)blockIdx.x * 256 + threadIdx.x; i8 < total8; i8 += (long long)gridDim.x * 256) {
    const long long i = i8 * 8;
    int k = 0;
#pragma unroll
    for (int j = 1; j < 15; ++j) if (i >= (long long)s.dst[j]) k = j;
    const long long loc = i - s.dst[k];
    short8 out;
    if (!s.src[k]) {
      for (int j = 0; j < 8; ++j) out[j] = 0;
    } else if (isbf) {
      out = *(const short8a*)((const u16*)s.src[k] + loc);
    } else {
      const float* fp = (const float*)s.src[k] + loc;
      const float4_ f0 = *(const float4a*)fp;
      const float4_ f1 = *(const float4a*)(fp + 4);
#pragma unroll
      for (int j = 0; j < 4; ++j) { out[j] = (short)f2b(f0[j]); out[j + 4] = (short)f2b(f1[j]); }
    }
    *(short8a*)(wt + i) = out;
  }
}

struct BSegs { const void* a[8]; const void* b[8]; int dst[8]; int n[8]; int np[8]; };
__global__ __launch_bounds__(256) void k_convb(BSegs s, float* __restrict__ bias, const int* __restrict__ flagp) {
  const int isbf = *flagp;
  for (int i = blockIdx.x * 256 + threadIdx.x; i < 9536; i += gridDim.x * 256) {
    int k = 0;
#pragma unroll
    for (int j = 1; j < 8; ++j) if (i >= s.dst[j]) k = j;
    const int loc = i - s.dst[k];
    float v = 0.f;
    if (loc < s.n[k]) {
      v = ldv(s.a[k], loc, isbf);
      if (s.b[k]) v += ldv(s.b[k], loc, isbf);
    }
    bias[i] = v;
  }
}

// ---------------- word embedding gather into cat[:,0:256] ----------------
__global__ __launch_bounds__(128) void k_wordgather(const int* __restrict__ sent, const void* __restrict__ wemb,
                                                    u16* __restrict__ cat, const int* __restrict__ flagp) {
  const int n = blockIdx.x;
  const int idx = sent[n];
  const int isbf = *flagp;
  for (int d = threadIdx.x; d < 256; d += 128)
    cat[(long long)n * 512 + d] = f2b(ldv(wemb, (long long)idx * 256 + d, isbf));
}

// ---------------- char biLSTM: 64 seqs/block, 16 steps, D=64 H=128 ----------------
__global__ __launch_bounds__(256) void k_char(const int* __restrict__ cs, const void* __restrict__ wchar,
                                              const u16* __restrict__ wihF, const u16* __restrict__ whhF,
                                              const u16* __restrict__ wihB, const u16* __restrict__ whhB,
                                              const float* __restrict__ biasF, const float* __restrict__ biasB,
                                              u16* __restrict__ cat, const int* __restrict__ flagp) {
  const int dir = blockIdx.y;
  const int nb = blockIdx.x;
  const u16* wih = dir ? wihB : wihF;
  const u16* whh = dir ? whhB : whhF;
  const float* bias = dir ? biasB : biasF;
  const int isbf = *flagp;
  __shared__ __align__(16) u16 xs[64][72];
  __shared__ __align__(16) u16 hs[64][136];
  const int tid = threadIdx.x, wv = tid >> 6, lane = tid & 63;
  for (int i = tid; i < 64 * 136; i += 256) ((u16*)hs)[i] = 0;
  float c[2][4][4];
#pragma unroll
  for (int a1 = 0; a1 < 2; ++a1)
#pragma unroll
    for (int a2 = 0; a2 < 4; ++a2)
#pragma unroll
      for (int a3 = 0; a3 < 4; ++a3) c[a1][a2][a3] = 0.f;

  for (int tt = 0; tt < 16; ++tt) {
    const int t = dir ? (15 - tt) : tt;
    {
      const int sid = tid >> 2, part = tid & 3;
      const int n = nb * 64 + sid;
      const int idx = cs[n * 16 + t];
#pragma unroll
      for (int q = 0; q < 16; ++q) {
        const int d2 = part * 16 + q;
        float v = 0.f;
        if (idx != 0) v = ldv(wchar, (long long)idx * 64 + d2, isbf);
        xs[sid][d2] = f2b(v);
      }
    }
    __syncthreads();
    float4_ acc[2][4][4];
#pragma unroll
    for (int ut = 0; ut < 2; ++ut)
#pragma unroll
      for (int g = 0; g < 4; ++g) {
        const float bv = bias[g * 128 + (wv + 4 * ut) * 16 + (lane & 15)];
#pragma unroll
        for (int rt = 0; rt < 4; ++rt) acc[ut][g][rt] = splat4(bv);
      }
#pragma unroll
    for (int kc = 0; kc < 6; ++kc) {
      short8 a[4];
      if (kc < 2) {
#pragma unroll
        for (int rt = 0; rt < 4; ++rt)
          a[rt] = *(const short8a*)&xs[rt * 16 + (lane & 15)][kc * 32 + (lane >> 4) * 8];
      } else {
#pragma unroll
        for (int rt = 0; rt < 4; ++rt)
          a[rt] = *(const short8a*)&hs[rt * 16 + (lane & 15)][(kc - 2) * 32 + (lane >> 4) * 8];
      }
#pragma unroll
      for (int ut = 0; ut < 2; ++ut)
#pragma unroll
        for (int g = 0; g < 4; ++g) {
          const int col = g * 128 + (wv + 4 * ut) * 16 + (lane & 15);
          short8 bfr;
          if (kc < 2) bfr = *(const short8a*)(wih + col * 64 + kc * 32 + (lane >> 4) * 8);
          else        bfr = *(const short8a*)(whh + col * 128 + (kc - 2) * 32 + (lane >> 4) * 8);
#pragma unroll
          for (int rt = 0; rt < 4; ++rt) acc[ut][g][rt] = MFMA16(a[rt], bfr, acc[ut][g][rt]);
        }
    }
    __syncthreads();
#pragma unroll
    for (int ut = 0; ut < 2; ++ut)
#pragma unroll
      for (int rt = 0; rt < 4; ++rt)
#pragma unroll
        for (int r = 0; r < 4; ++r) {
          const float iv = acc[ut][0][rt][r];
          const float fv = acc[ut][1][rt][r];
          const float gv = acc[ut][2][rt][r];
          const float ov = acc[ut][3][rt][r];
          float& cc = c[ut][rt][r];
          cc = sigm(fv) * cc + sigm(iv) * tanh_(gv);
          const float h = sigm(ov) * tanh_(cc);
          const int seq = rt * 16 + (lane >> 4) * 4 + r;
          const int u = (wv + 4 * ut) * 16 + (lane & 15);
          const u16 hv = f2b(h);
          hs[seq][u] = hv;
          if (tt == 15) cat[(long long)(nb * 64 + seq) * 512 + 256 + dir * 128 + u] = hv;
        }
  }
}

// ---------------- generic MFMA GEMM ----------------
template <int TM, int TN, int PERM, int OUTM>
__global__ __launch_bounds__(256) void k_gemm(const u16* __restrict__ A, const u16* __restrict__ Wt,
                                              const float* __restrict__ bias, void* __restrict__ Cout,
                                              const int N, const int K, const int ldc,
                                              const int* __restrict__ flagp) {
  constexpr int RT = TM / 16;
  constexpr int CPW = TN / 64;
  const int bm = blockIdx.x, bn = blockIdx.y;
  const int tid = threadIdx.x, wv = tid >> 6, lane = tid & 63;
  __shared__ __align__(16) u16 As[TM][72];
  float4_ acc[CPW][RT];
#pragma unroll
  for (int ci = 0; ci < CPW; ++ci)
#pragma unroll
    for (int rt = 0; rt < RT; ++rt) acc[ci][rt] = splat4(0.f);
  const int nk = K >> 6;
  for (int kc = 0; kc < nk; ++kc) {
    __syncthreads();
    for (int idx = tid; idx < TM * 4; idx += 256) {
      const int r = idx >> 2, sg = idx & 3;
      const u16* src = A + (long long)(bm * TM + r) * K + kc * 64 + sg * 16;
      *(short8a*)&As[r][sg * 16] = *(const short8a*)src;
      *(short8a*)&As[r][sg * 16 + 8] = *(const short8a*)(src + 8);
    }
    __syncthreads();
#pragma unroll
    for (int kk = 0; kk < 2; ++kk) {
      short8 af[RT];
#pragma unroll
      for (int rt = 0; rt < RT; ++rt)
        af[rt] = *(const short8a*)&As[rt * 16 + (lane & 15)][kk * 32 + (lane >> 4) * 8];
#pragma unroll
      for (int ci = 0; ci < CPW; ++ci) {
        const int ct = wv + ci * 4;
        const short8 bf = *(const short8a*)(Wt + (long long)(bn * TN + ct * 16 + (lane & 15)) * K +
                                            kc * 64 + kk * 32 + (lane >> 4) * 8);
#pragma unroll
        for (int rt = 0; rt < RT; ++rt) acc[ci][rt] = MFMA16(af[rt], bf, acc[ci][rt]);
      }
    }
  }
  const int isbf = (OUTM == 1) ? *flagp : 0;
#pragma unroll
  for (int ci = 0; ci < CPW; ++ci)
#pragma unroll
    for (int rt = 0; rt < RT; ++rt)
#pragma unroll
      for (int r = 0; r < 4; ++r) {
        const int row = bm * TM + rt * 16 + (lane >> 4) * 4 + r;
        const int col = bn * TN + (wv + ci * 4) * 16 + (lane & 15);
        if (col < N) {
          const float v = acc[ci][rt][r] + bias[col];
          long long orow;
          if (PERM == 0) orow = row;
          else if (PERM == 1) orow = (long long)(row & 255) * 64 + (row >> 8);
          else orow = (long long)(row & 63) * 256 + (row >> 6);
          if (OUTM == 0) ((u16*)Cout)[orow * ldc + col] = f2b(v);
          else if (isbf) ((u16*)Cout)[orow * ldc + col] = f2b(v);
          else ((float*)Cout)[orow * ldc + col] = v;
        }
      }
}

// ---------------- persistent LSTM scan (one layer, both dirs) ----------------
// grid (16, 2=dir), 512 threads (8 waves). Block owns 32 units. Wave w =
// (gate g=w&3, K-half kh=w>>2): weights 16 short8 = 64 VGPR, loop-carried asm
// pin. Per step: cooperative bypass h stage (16 u64/thread -> swizzled LDS),
// 64 MFMA/wave from LDS fragments, K-half partials through padded LDS
// exchange, 4 outputs/thread activation, u64 bypass publish, flag handshake.
// NO cache fences -> weights/pre/L1/L2 stay warm for all 256 steps.
__global__ __launch_bounds__(512, 1) void k_scan(const u16* __restrict__ pre0, const u16* __restrict__ pre1,
                                                 const u16* __restrict__ whh0, const u16* __restrict__ whh1,
                                                 u16* __restrict__ o_out, u16* __restrict__ hbuf,
                                                 int* __restrict__ flags) {
  const int dir = blockIdx.y, blk = blockIdx.x;
  const u16* __restrict__ pre = dir ? pre1 : pre0;
  const u16* __restrict__ whh = dir ? whh1 : whh0;
  u16* hb = hbuf + dir * (2 * 64 * 512);
  int* myflags = flags + dir * 16;
  const int u0 = blk * 32;
  __shared__ __align__(16) u16 hstage[64 * 512];    // 64KB, XOR-swizzled rows
  __shared__ __align__(16) float xch[8 * 64 * 40];  // 80KB [kh*4+g][bb][40pad]
  const int tid = threadIdx.x, lane = tid & 63;
  const int wv = tid >> 6;
  const int l15 = lane & 15, q = lane >> 4;
  const int g = wv & 3, kh = wv >> 2;

  // weight fragments: rows u0 + ci*16 + l15 of gate g, k = kh*256 + kc*32 + q*8
  float4_ swf[2][8];
#pragma unroll
  for (int ci = 0; ci < 2; ++ci)
#pragma unroll
    for (int kc = 0; kc < 8; ++kc)
      swf[ci][kc] = *(const float4a*)(whh + (long long)(g * 512 + u0 + ci * 16 + l15) * 512 +
                                      kh * 256 + kc * 32 + q * 8);

  // activation ownership: batch bb, unit quad u0+uu .. +4
  const int bb = tid >> 3;
  const int uu = (tid & 7) * 4;
  float c4[4];
#pragma unroll
  for (int j = 0; j < 4; ++j) c4[j] = 0.f;

  // stage role: row srow, 128B segment sseg
  const int srow = tid & 63;
  const int sseg = tid >> 6;
  const int skey = (srow & 7) << 4;

  ull pr[4], prn[4];
  {
    const int t0 = dir ? 255 : 0;
    const u16* pb = pre + (long long)(t0 * 64 + bb) * 2048 + u0 + uu;
#pragma unroll
    for (int g2 = 0; g2 < 4; ++g2) pr[g2] = *(const ulla*)(pb + g2 * 512);
  }

  for (int tt = 0; tt < 256; ++tt) {
    const int t = dir ? (255 - tt) : tt;
    const u16* hrd = hb + (tt & 1) * 32768;
    u16* hwr = hb + ((tt + 1) & 1) * 32768;

    // ---- cooperative bypass stage: 16 u64/thread -> swizzled LDS b128 ----
    {
      const ull* sgp = (const ull*)(const void*)(hrd + srow * 512 + sseg * 64);
      ull sv[16];
#pragma unroll
      for (int i = 0; i < 16; ++i)
        sv[i] = __hip_atomic_load(sgp + i, __ATOMIC_RELAXED, __HIP_MEMORY_SCOPE_AGENT);
      char* swb = (char*)hstage + srow * 1024;
#pragma unroll
      for (int i = 0; i < 8; ++i) {
        struct U2 { ull a, b; } u2;
        u2.a = sv[2 * i]; u2.b = sv[2 * i + 1];
        *(float4a*)(swb + ((sseg * 128 + i * 16) ^ skey)) = __builtin_bit_cast(float4_, u2);
      }
    }
    __syncthreads();

    // ---- MFMA: acc[ci][bt] over this wave's (gate, K-half) ----
    float4_ acc[2][4];
#pragma unroll
    for (int ci = 0; ci < 2; ++ci)
#pragma unroll
      for (int bt = 0; bt < 4; ++bt) acc[ci][bt] = splat4(0.f);
    const char* hsb = (const char*)hstage;
#pragma unroll
    for (int kc = 0; kc < 8; ++kc) {
      const short8 w0 = __builtin_bit_cast(short8, swf[0][kc]);
      const short8 w1 = __builtin_bit_cast(short8, swf[1][kc]);
#pragma unroll
      for (int bt = 0; bt < 4; ++bt) {
        const int row = bt * 16 + l15;
        const short8 A = *(const short8a*)(hsb + row * 1024 +
                          ((kh * 512 + kc * 64 + q * 16) ^ ((row & 7) << 4)));
        acc[0][bt] = MFMA16(w0, A, acc[0][bt]);
        acc[1][bt] = MFMA16(w1, A, acc[1][bt]);
      }
    }

    // ---- exchange K-half partials ----
#pragma unroll
    for (int ci = 0; ci < 2; ++ci)
#pragma unroll
      for (int bt = 0; bt < 4; ++bt)
        *(float4a*)&xch[((kh * 4 + g) * 64 + bt * 16 + l15) * 40 + ci * 16 + q * 4] = acc[ci][bt];
    __syncthreads();

    // ---- activation: 4 outputs (batch bb, units u0+uu..+3) ----
    float4_ gv[4];
#pragma unroll
    for (int g2 = 0; g2 < 4; ++g2) {
      const float4_ p0 = *(const float4a*)&xch[(g2 * 64 + bb) * 40 + uu];
      const float4_ p1 = *(const float4a*)&xch[((4 + g2) * 64 + bb) * 40 + uu];
      gv[g2] = p0 + p1;
    }
    ull hv = 0;
#pragma unroll
    for (int j = 0; j < 4; ++j) {
      const float iv = gv[0][j] + b2f((u16)(pr[0] >> (16 * j)));
      const float fv = gv[1][j] + b2f((u16)(pr[1] >> (16 * j)));
      const float gg = gv[2][j] + b2f((u16)(pr[2] >> (16 * j)));
      const float ov = gv[3][j] + b2f((u16)(pr[3] >> (16 * j)));
      c4[j] = sigm(fv) * c4[j] + sigm(iv) * tanh_(gg);
      const float h = sigm(ov) * tanh_(c4[j]);
      hv |= (ull)f2b(h) << (16 * j);
    }
    __hip_atomic_store((ull*)(hwr + bb * 512 + u0 + uu), hv,
                       __ATOMIC_RELAXED, __HIP_MEMORY_SCOPE_AGENT);
    asm volatile("s_waitcnt vmcnt(0)" ::: "memory");  // h at coherence point
    __syncthreads();
    if (tid == 0)
      __hip_atomic_store(&myflags[blk], tt + 1, __ATOMIC_RELAXED, __HIP_MEMORY_SCOPE_AGENT);
    // overlap poll: o_out store + next-step pre prefetch
    *(ulla*)(o_out + (long long)(t * 64 + bb) * 1024 + dir * 512 + u0 + uu) = hv;
    {
      const int ttn = (tt < 255) ? tt + 1 : tt;
      const int tn = dir ? (255 - ttn) : ttn;
      const u16* pb = pre + (long long)(tn * 64 + bb) * 2048 + u0 + uu;
#pragma unroll
      for (int g2 = 0; g2 < 4; ++g2) prn[g2] = *(const ulla*)(pb + g2 * 512);
    }
    if (tt != 255) {
      if (wv == 0) {
        int v = __hip_atomic_load(&myflags[l15], __ATOMIC_RELAXED, __HIP_MEMORY_SCOPE_AGENT);
        while (__all(v >= tt + 1) == 0) {
          __builtin_amdgcn_s_sleep(1);
          v = __hip_atomic_load(&myflags[l15], __ATOMIC_RELAXED, __HIP_MEMORY_SCOPE_AGENT);
        }
      }
      __syncthreads();  // all waves held until h_{t+1} fully published
    }
#pragma unroll
    for (int g2 = 0; g2 < 4; ++g2) pr[g2] = prn[g2];
    // loop-carried opaque pin: weights must stay live in VGPRs (no remat)
#pragma unroll
    for (int ci = 0; ci < 2; ++ci)
#pragma unroll
      for (int kc = 0; kc < 8; ++kc) asm volatile("" : "+v"(swf[ci][kc]));
  }
}

// ---------------- launcher ----------------
static constexpr long long OFF_WT = 0;
static constexpr long long OFF_BIAS = 19660800;
static constexpr long long OFF_CAT = 19698944;
static constexpr long long OFF_EMB = 36476160;
static constexpr long long OFF_PRE = 44864768;
static constexpr long long OFF_O1 = 179082496;
static constexpr long long OFF_O2 = 212636928;
static constexpr long long OFF_SYNC = 246191360;
static constexpr long long SYNC_BYTES = 4096 + 524288;
static constexpr long long OFF_FLAG = OFF_SYNC + SYNC_BYTES;

extern "C" void kernel_launch(void* const* d_in, const int* in_sizes, int n_in,
                              void* d_out, int out_size, void* d_ws, size_t ws_size,
                              hipStream_t stream) {
  char* ws = (char*)d_ws;
  u16* wt = (u16*)(ws + OFF_WT);
  float* biasp = (float*)(ws + OFF_BIAS);
  u16* cat = (u16*)(ws + OFF_CAT);
  u16* emb = (u16*)(ws + OFF_EMB);
  u16* pre0 = (u16*)(ws + OFF_PRE);
  u16* pre1 = pre0 + (long long)16384 * 2048;
  u16* o1 = (u16*)(ws + OFF_O1);
  u16* o2 = (u16*)(ws + OFF_O2);
  int* cnt1 = (int*)(ws + OFF_SYNC);
  int* cnt2 = cnt1 + 512;
  u16* h1 = (u16*)(ws + OFF_SYNC + 4096);
  u16* h2 = h1 + 131072;
  int* flag = (int*)(ws + OFF_FLAG);

  hipMemsetAsync(ws + OFF_SYNC, 0, SYNC_BYTES, stream);
  k_detect<<<1, 256, 0, stream>>>((const unsigned*)d_in[30], flag);

  WSegs wsg;
  const int widx[14] = {4, 5, 8, 9, 12, 13, 16, 17, 20, 21, 24, 25, 28, 30};
  const int wdst[15] = {0, 32768, 98304, 131072, 196608, 720896, 1769472, 2293760,
                        3342336, 5439488, 6488064, 8585216, 9633792, 9764864, 9816064};
  const int wn[15] = {32768, 65536, 32768, 65536, 524288, 1048576, 524288, 1048576,
                      2097152, 1048576, 2097152, 1048576, 131072, 51200, 14336};
  for (int j = 0; j < 14; ++j) { wsg.src[j] = d_in[widx[j]]; wsg.dst[j] = wdst[j]; wsg.n[j] = wn[j]; }
  wsg.src[14] = nullptr; wsg.dst[14] = wdst[14]; wsg.n[14] = wn[14];
  k_convw<<<1200, 256, 0, stream>>>(wsg, wt, flag);

  BSegs bsg;
  const int ba[8] = {6, 10, 14, 18, 22, 26, 29, 31};
  const int bb[8] = {7, 11, 15, 19, 23, 27, -1, -1};
  const int bdst[8] = {0, 512, 1024, 3072, 5120, 7168, 9216, 9472};
  const int bn_[8] = {512, 512, 2048, 2048, 2048, 2048, 256, 50};
  const int bnp[8] = {512, 512, 2048, 2048, 2048, 2048, 256, 64};
  for (int j = 0; j < 8; ++j) {
    bsg.a[j] = d_in[ba[j]];
    bsg.b[j] = (bb[j] >= 0) ? d_in[bb[j]] : nullptr;
    bsg.dst[j] = bdst[j]; bsg.n[j] = bn_[j]; bsg.np[j] = bnp[j];
  }
  k_convb<<<40, 256, 0, stream>>>(bsg, biasp, flag);

  k_wordgather<<<16384, 128, 0, stream>>>((const int*)d_in[0], d_in[2], cat, flag);
  k_char<<<dim3(256, 2), 256, 0, stream>>>((const int*)d_in[1], d_in[3],
                                           wt + 0, wt + 32768, wt + 98304, wt + 131072,
                                           biasp + 0, biasp + 512, cat, flag);
  k_gemm<64, 64, 1, 0><<<dim3(256, 4), 256, 0, stream>>>(cat, wt + 9633792, biasp + 9216, emb, 256, 512, 256, flag);
  k_gemm<128, 256, 0, 0><<<dim3(128, 8), 256, 0, stream>>>(emb, wt + 196608, biasp + 1024, pre0, 2048, 256, 2048, flag);
  k_gemm<128, 256, 0, 0><<<dim3(128, 8), 256, 0, stream>>>(emb, wt + 1769472, biasp + 3072, pre1, 2048, 256, 2048, flag);
  k_scan<<<dim3(16, 2), 512, 0, stream>>>(pre0, pre1, wt + 720896, wt + 2293760, o1, h1, cnt1);
  k_gemm<128, 256, 0, 0><<<dim3(128, 8), 256, 0, stream>>>(o1, wt + 3342336, biasp + 5120, pre0, 2048, 1024, 2048, flag);
  k_gemm<128, 256, 0, 0><<<dim3(128, 8), 256, 0, stream>>>(o1, wt + 6488064, biasp + 7168, pre1, 2048, 1024, 2048, flag);
  k_scan<<<dim3(16, 2), 512, 0, stream>>>(pre0, pre1, wt + 5439488, wt + 8585216, o2, h2, cnt2);
  k_gemm<64, 64, 2, 1><<<dim3(256, 1), 256, 0, stream>>>(o2, wt + 9764864, biasp + 9472, d_out, 50, 1024, 50, flag);
}

// Round 8
// 4290.772 us; speedup vs baseline: 2.2762x; 1.3476x over previous
//
// BiLSTM tagger — MI355X. Round 8: h ring buffer -> plain-load consume.
// Post-mortem R7: MfmaUtil 1.1%/VALUBusy 2% at 9.7us/step = pure stall; the
// 16 agent-atomic u64 stage loads/lane serialize on MALL latency (R6 showed
// atomics don't pipeline). Fix: h lives in the o_out ring — each line written
// once (sc1 write-through) and read only after flag publish -> first-touch
// consumers can use PLAIN b128 loads (no stale copy can exist). Publish is a
// single sc1 u64/thread. Flags monotonic -> no upper barrier. xch pad 36
// (<=2-way both sides). Zero-slot zbuf serves step 0.
#include <hip/hip_runtime.h>

typedef unsigned short u16;
typedef unsigned long long ull;
typedef short short8 __attribute__((ext_vector_type(8)));
typedef float float4_ __attribute__((ext_vector_type(4)));
typedef short8 short8a __attribute__((may_alias));
typedef float4_ float4a __attribute__((may_alias));
typedef ull ulla __attribute__((may_alias));

#define MFMA16(a, b, c) __builtin_amdgcn_mfma_f32_16x16x32_bf16((a), (b), (c), 0, 0, 0)

static __device__ __forceinline__ float b2f(u16 v) { return __uint_as_float(((unsigned)v) << 16); }
static __device__ __forceinline__ u16 f2b(float f) {
  unsigned x = __float_as_uint(f);
  return (u16)((x + 0x7fffu + ((x >> 16) & 1u)) >> 16);
}
static __device__ __forceinline__ float ldv(const void* p, long long i, int isbf) {
  return isbf ? b2f(((const u16*)p)[i]) : ((const float*)p)[i];
}
static __device__ __forceinline__ float sigm(float x) { return 1.f / (1.f + __expf(-x)); }
static __device__ __forceinline__ float tanh_(float x) { return 1.f - 2.f / (__expf(2.f * x) + 1.f); }
static __device__ __forceinline__ float4_ splat4(float v) { float4_ r; r[0]=v; r[1]=v; r[2]=v; r[3]=v; return r; }

// ---------------- dtype detection (f32 vs bf16 input buffers) ----------------
__global__ __launch_bounds__(256) void k_detect(const unsigned* __restrict__ wtag, int* __restrict__ flag) {
  __shared__ int cs;
  if (threadIdx.x == 0) cs = 0;
  __syncthreads();
  int hits = 0;
  for (int i = threadIdx.x; i < 1024; i += 256) {
    unsigned b = (wtag[i] >> 8) & 0x7fu;
    hits += (b >= 0x36u && b <= 0x3fu) ? 1 : 0;
  }
  atomicAdd(&cs, hits);
  __syncthreads();
  if (threadIdx.x == 0) *flag = (cs > 512) ? 1 : 0;
}

// ---------------- weight conversion to bf16 workspace (x8 vectorized) ----------------
struct WSegs { const void* src[15]; int dst[15]; int n[15]; };
__global__ __launch_bounds__(256) void k_convw(WSegs s, u16* __restrict__ wt, const int* __restrict__ flagp) {
  const int isbf = *flagp;
  const long long total8 = 9830400 / 8;
  for (long long i8 = (long long)blockIdx.x * 256 + threadIdx.x; i8 < total8; i8 += (long long)gridDim.x * 256) {
    const long long i = i8 * 8;
    int k = 0;
#pragma unroll
    for (int j = 1; j < 15; ++j) if (i >= (long long)s.dst[j]) k = j;
    const long long loc = i - s.dst[k];
    short8 out;
    if (!s.src[k]) {
      for (int j = 0; j < 8; ++j) out[j] = 0;
    } else if (isbf) {
      out = *(const short8a*)((const u16*)s.src[k] + loc);
    } else {
      const float* fp = (const float*)s.src[k] + loc;
      const float4_ f0 = *(const float4a*)fp;
      const float4_ f1 = *(const float4a*)(fp + 4);
#pragma unroll
      for (int j = 0; j < 4; ++j) { out[j] = (short)f2b(f0[j]); out[j + 4] = (short)f2b(f1[j]); }
    }
    *(short8a*)(wt + i) = out;
  }
}

struct BSegs { const void* a[8]; const void* b[8]; int dst[8]; int n[8]; int np[8]; };
__global__ __launch_bounds__(256) void k_convb(BSegs s, float* __restrict__ bias, const int* __restrict__ flagp) {
  const int isbf = *flagp;
  for (int i = blockIdx.x * 256 + threadIdx.x; i < 9536; i += gridDim.x * 256) {
    int k = 0;
#pragma unroll
    for (int j = 1; j < 8; ++j) if (i >= s.dst[j]) k = j;
    const int loc = i - s.dst[k];
    float v = 0.f;
    if (loc < s.n[k]) {
      v = ldv(s.a[k], loc, isbf);
      if (s.b[k]) v += ldv(s.b[k], loc, isbf);
    }
    bias[i] = v;
  }
}

// ---------------- word embedding gather into cat[:,0:256] ----------------
__global__ __launch_bounds__(128) void k_wordgather(const int* __restrict__ sent, const void* __restrict__ wemb,
                                                    u16* __restrict__ cat, const int* __restrict__ flagp) {
  const int n = blockIdx.x;
  const int idx = sent[n];
  const int isbf = *flagp;
  for (int d = threadIdx.x; d < 256; d += 128)
    cat[(long long)n * 512 + d] = f2b(ldv(wemb, (long long)idx * 256 + d, isbf));
}

// ---------------- char biLSTM: 64 seqs/block, 16 steps, D=64 H=128 ----------------
__global__ __launch_bounds__(256) void k_char(const int* __restrict__ cs, const void* __restrict__ wchar,
                                              const u16* __restrict__ wihF, const u16* __restrict__ whhF,
                                              const u16* __restrict__ wihB, const u16* __restrict__ whhB,
                                              const float* __restrict__ biasF, const float* __restrict__ biasB,
                                              u16* __restrict__ cat, const int* __restrict__ flagp) {
  const int dir = blockIdx.y;
  const int nb = blockIdx.x;
  const u16* wih = dir ? wihB : wihF;
  const u16* whh = dir ? whhB : whhF;
  const float* bias = dir ? biasB : biasF;
  const int isbf = *flagp;
  __shared__ __align__(16) u16 xs[64][72];
  __shared__ __align__(16) u16 hs[64][136];
  const int tid = threadIdx.x, wv = tid >> 6, lane = tid & 63;
  for (int i = tid; i < 64 * 136; i += 256) ((u16*)hs)[i] = 0;
  float c[2][4][4];
#pragma unroll
  for (int a1 = 0; a1 < 2; ++a1)
#pragma unroll
    for (int a2 = 0; a2 < 4; ++a2)
#pragma unroll
      for (int a3 = 0; a3 < 4; ++a3) c[a1][a2][a3] = 0.f;

  for (int tt = 0; tt < 16; ++tt) {
    const int t = dir ? (15 - tt) : tt;
    {
      const int sid = tid >> 2, part = tid & 3;
      const int n = nb * 64 + sid;
      const int idx = cs[n * 16 + t];
#pragma unroll
      for (int q = 0; q < 16; ++q) {
        const int d2 = part * 16 + q;
        float v = 0.f;
        if (idx != 0) v = ldv(wchar, (long long)idx * 64 + d2, isbf);
        xs[sid][d2] = f2b(v);
      }
    }
    __syncthreads();
    float4_ acc[2][4][4];
#pragma unroll
    for (int ut = 0; ut < 2; ++ut)
#pragma unroll
      for (int g = 0; g < 4; ++g) {
        const float bv = bias[g * 128 + (wv + 4 * ut) * 16 + (lane & 15)];
#pragma unroll
        for (int rt = 0; rt < 4; ++rt) acc[ut][g][rt] = splat4(bv);
      }
#pragma unroll
    for (int kc = 0; kc < 6; ++kc) {
      short8 a[4];
      if (kc < 2) {
#pragma unroll
        for (int rt = 0; rt < 4; ++rt)
          a[rt] = *(const short8a*)&xs[rt * 16 + (lane & 15)][kc * 32 + (lane >> 4) * 8];
      } else {
#pragma unroll
        for (int rt = 0; rt < 4; ++rt)
          a[rt] = *(const short8a*)&hs[rt * 16 + (lane & 15)][(kc - 2) * 32 + (lane >> 4) * 8];
      }
#pragma unroll
      for (int ut = 0; ut < 2; ++ut)
#pragma unroll
        for (int g = 0; g < 4; ++g) {
          const int col = g * 128 + (wv + 4 * ut) * 16 + (lane & 15);
          short8 bfr;
          if (kc < 2) bfr = *(const short8a*)(wih + col * 64 + kc * 32 + (lane >> 4) * 8);
          else        bfr = *(const short8a*)(whh + col * 128 + (kc - 2) * 32 + (lane >> 4) * 8);
#pragma unroll
          for (int rt = 0; rt < 4; ++rt) acc[ut][g][rt] = MFMA16(a[rt], bfr, acc[ut][g][rt]);
        }
    }
    __syncthreads();
#pragma unroll
    for (int ut = 0; ut < 2; ++ut)
#pragma unroll
      for (int rt = 0; rt < 4; ++rt)
#pragma unroll
        for (int r = 0; r < 4; ++r) {
          const float iv = acc[ut][0][rt][r];
          const float fv = acc[ut][1][rt][r];
          const float gv = acc[ut][2][rt][r];
          const float ov = acc[ut][3][rt][r];
          float& cc = c[ut][rt][r];
          cc = sigm(fv) * cc + sigm(iv) * tanh_(gv);
          const float h = sigm(ov) * tanh_(cc);
          const int seq = rt * 16 + (lane >> 4) * 4 + r;
          const int u = (wv + 4 * ut) * 16 + (lane & 15);
          const u16 hv = f2b(h);
          hs[seq][u] = hv;
          if (tt == 15) cat[(long long)(nb * 64 + seq) * 512 + 256 + dir * 128 + u] = hv;
        }
  }
}

// ---------------- generic MFMA GEMM ----------------
template <int TM, int TN, int PERM, int OUTM>
__global__ __launch_bounds__(256) void k_gemm(const u16* __restrict__ A, const u16* __restrict__ Wt,
                                              const float* __restrict__ bias, void* __restrict__ Cout,
                                              const int N, const int K, const int ldc,
                                              const int* __restrict__ flagp) {
  constexpr int RT = TM / 16;
  constexpr int CPW = TN / 64;
  const int bm = blockIdx.x, bn = blockIdx.y;
  const int tid = threadIdx.x, wv = tid >> 6, lane = tid & 63;
  __shared__ __align__(16) u16 As[TM][72];
  float4_ acc[CPW][RT];
#pragma unroll
  for (int ci = 0; ci < CPW; ++ci)
#pragma unroll
    for (int rt = 0; rt < RT; ++rt) acc[ci][rt] = splat4(0.f);
  const int nk = K >> 6;
  for (int kc = 0; kc < nk; ++kc) {
    __syncthreads();
    for (int idx = tid; idx < TM * 4; idx += 256) {
      const int r = idx >> 2, sg = idx & 3;
      const u16* src = A + (long long)(bm * TM + r) * K + kc * 64 + sg * 16;
      *(short8a*)&As[r][sg * 16] = *(const short8a*)src;
      *(short8a*)&As[r][sg * 16 + 8] = *(const short8a*)(src + 8);
    }
    __syncthreads();
#pragma unroll
    for (int kk = 0; kk < 2; ++kk) {
      short8 af[RT];
#pragma unroll
      for (int rt = 0; rt < RT; ++rt)
        af[rt] = *(const short8a*)&As[rt * 16 + (lane & 15)][kk * 32 + (lane >> 4) * 8];
#pragma unroll
      for (int ci = 0; ci < CPW; ++ci) {
        const int ct = wv + ci * 4;
        const short8 bf = *(const short8a*)(Wt + (long long)(bn * TN + ct * 16 + (lane & 15)) * K +
                                            kc * 64 + kk * 32 + (lane >> 4) * 8);
#pragma unroll
        for (int rt = 0; rt < RT; ++rt) acc[ci][rt] = MFMA16(af[rt], bf, acc[ci][rt]);
      }
    }
  }
  const int isbf = (OUTM == 1) ? *flagp : 0;
#pragma unroll
  for (int ci = 0; ci < CPW; ++ci)
#pragma unroll
    for (int rt = 0; rt < RT; ++rt)
#pragma unroll
      for (int r = 0; r < 4; ++r) {
        const int row = bm * TM + rt * 16 + (lane >> 4) * 4 + r;
        const int col = bn * TN + (wv + ci * 4) * 16 + (lane & 15);
        if (col < N) {
          const float v = acc[ci][rt][r] + bias[col];
          long long orow;
          if (PERM == 0) orow = row;
          else if (PERM == 1) orow = (long long)(row & 255) * 64 + (row >> 8);
          else orow = (long long)(row & 63) * 256 + (row >> 6);
          if (OUTM == 0) ((u16*)Cout)[orow * ldc + col] = f2b(v);
          else if (isbf) ((u16*)Cout)[orow * ldc + col] = f2b(v);
          else ((float*)Cout)[orow * ldc + col] = v;
        }
      }
}

// ---------------- persistent LSTM scan (one layer, both dirs) ----------------
// grid (16, 2=dir), 512 threads (8 waves = gate g x K-half kh). h ring =
// o_out itself: publish = ONE sc1 u64/thread (write-through); consume = plain
// b128 loads of o_out[t-1] (first-touch lines, can't be stale) staged once
// per block into swizzled LDS. zbuf = zeroed slot for step 0. Flags are
// monotonic per-block step counters; no upper barrier, no fences anywhere.
__global__ __launch_bounds__(512, 1) void k_scan(const u16* __restrict__ pre0, const u16* __restrict__ pre1,
                                                 const u16* __restrict__ whh0, const u16* __restrict__ whh1,
                                                 u16* __restrict__ o_out, const u16* __restrict__ zbuf,
                                                 int* __restrict__ flags) {
  const int dir = blockIdx.y, blk = blockIdx.x;
  const u16* __restrict__ pre = dir ? pre1 : pre0;
  const u16* __restrict__ whh = dir ? whh1 : whh0;
  int* myflags = flags + dir * 16;
  const int u0 = blk * 32;
  __shared__ __align__(16) u16 hstage[64 * 512];    // 64KB, XOR-swizzled rows
  __shared__ __align__(16) float xch[8 * 64 * 36];  // 72KB [kh*4+g][b][36pad]
  const int tid = threadIdx.x, lane = tid & 63;
  const int wv = tid >> 6;
  const int l15 = lane & 15, q = lane >> 4;
  const int g = wv & 3, kh = wv >> 2;

  // weight fragments: rows u0 + ci*16 + l15 of gate g, k = kh*256 + kc*32 + q*8
  float4_ swf[2][8];
#pragma unroll
  for (int ci = 0; ci < 2; ++ci)
#pragma unroll
    for (int kc = 0; kc < 8; ++kc)
      swf[ci][kc] = *(const float4a*)(whh + (long long)(g * 512 + u0 + ci * 16 + l15) * 512 +
                                      kh * 256 + kc * 32 + q * 8);

  // activation ownership: batch bb, unit quad u0+uu .. +4
  const int bb = tid >> 3;
  const int uu = (tid & 7) * 4;
  float c4[4];
#pragma unroll
  for (int j = 0; j < 4; ++j) c4[j] = 0.f;

  // stage role: row srow (batch), 128B segment sseg of the 1KB dir-half row
  const int srow = tid & 63;
  const int sseg = tid >> 6;
  const int skey = (srow & 7) << 4;

  ull pr[4], prn[4];
  {
    const int t0 = dir ? 255 : 0;
    const u16* pb = pre + (long long)(t0 * 64 + bb) * 2048 + u0 + uu;
#pragma unroll
    for (int g2 = 0; g2 < 4; ++g2) pr[g2] = *(const ulla*)(pb + g2 * 512);
  }

  for (int tt = 0; tt < 256; ++tt) {
    const int t = dir ? (255 - tt) : tt;

    // ---- stage h_{t-1}: plain b128 loads (first-touch ring) -> swizzled LDS ----
    {
      const u16* rowp;
      if (tt == 0) {
        rowp = zbuf + srow * 1024 + dir * 512;
      } else {
        const int tp = dir ? (t + 1) : (t - 1);
        rowp = o_out + (long long)(tp * 64 + srow) * 1024 + dir * 512;
      }
      const u16* sp = rowp + sseg * 64;
      char* swb = (char*)hstage + srow * 1024;
#pragma unroll
      for (int i = 0; i < 8; ++i) {
        const float4_ v = *(const float4a*)(sp + i * 8);
        *(float4a*)(swb + ((sseg * 128 + i * 16) ^ skey)) = v;
      }
    }
    __syncthreads();

    // ---- MFMA: acc[ci][bt] over this wave's (gate, K-half) ----
    float4_ acc[2][4];
#pragma unroll
    for (int ci = 0; ci < 2; ++ci)
#pragma unroll
      for (int bt = 0; bt < 4; ++bt) acc[ci][bt] = splat4(0.f);
    const char* hsb = (const char*)hstage;
#pragma unroll
    for (int kc = 0; kc < 8; ++kc) {
      const short8 w0 = __builtin_bit_cast(short8, swf[0][kc]);
      const short8 w1 = __builtin_bit_cast(short8, swf[1][kc]);
#pragma unroll
      for (int bt = 0; bt < 4; ++bt) {
        const int row = bt * 16 + l15;
        const short8 A = *(const short8a*)(hsb + row * 1024 +
                          ((kh * 512 + kc * 64 + q * 16) ^ ((row & 7) << 4)));
        acc[0][bt] = MFMA16(w0, A, acc[0][bt]);
        acc[1][bt] = MFMA16(w1, A, acc[1][bt]);
      }
    }

    // ---- exchange K-half partials ([krow][b][36pad], <=2-way both sides) ----
#pragma unroll
    for (int ci = 0; ci < 2; ++ci)
#pragma unroll
      for (int bt = 0; bt < 4; ++bt)
        *(float4a*)&xch[((kh * 4 + g) * 64 + bt * 16 + l15) * 36 + ci * 16 + q * 4] = acc[ci][bt];
    __syncthreads();

    // ---- activation: 4 outputs (batch bb, units u0+uu..+3) ----
    float4_ gv[4];
#pragma unroll
    for (int g2 = 0; g2 < 4; ++g2) {
      const float4_ p0 = *(const float4a*)&xch[(g2 * 64 + bb) * 36 + uu];
      const float4_ p1 = *(const float4a*)&xch[((4 + g2) * 64 + bb) * 36 + uu];
      gv[g2] = p0 + p1;
    }
    ull hv = 0;
#pragma unroll
    for (int j = 0; j < 4; ++j) {
      const float iv = gv[0][j] + b2f((u16)(pr[0] >> (16 * j)));
      const float fv = gv[1][j] + b2f((u16)(pr[1] >> (16 * j)));
      const float gg = gv[2][j] + b2f((u16)(pr[2] >> (16 * j)));
      const float ov = gv[3][j] + b2f((u16)(pr[3] >> (16 * j)));
      c4[j] = sigm(fv) * c4[j] + sigm(iv) * tanh_(gg);
      const float h = sigm(ov) * tanh_(c4[j]);
      hv |= (ull)f2b(h) << (16 * j);
    }
    // single write-through publish into the ring (= o_out)
    __hip_atomic_store((ull*)(o_out + (long long)(t * 64 + bb) * 1024 + dir * 512 + u0 + uu), hv,
                       __ATOMIC_RELAXED, __HIP_MEMORY_SCOPE_AGENT);
    asm volatile("s_waitcnt vmcnt(0)" ::: "memory");  // h at coherence point
    __syncthreads();
    if (tid == 0)
      __hip_atomic_store(&myflags[blk], tt + 1, __ATOMIC_RELAXED, __HIP_MEMORY_SCOPE_AGENT);
    // overlap poll: next-step pre prefetch
    {
      const int ttn = (tt < 255) ? tt + 1 : tt;
      const int tn = dir ? (255 - ttn) : ttn;
      const u16* pb = pre + (long long)(tn * 64 + bb) * 2048 + u0 + uu;
#pragma unroll
      for (int g2 = 0; g2 < 4; ++g2) prn[g2] = *(const ulla*)(pb + g2 * 512);
    }
    if (tt != 255) {
      if (wv == 0) {
        int v = __hip_atomic_load(&myflags[l15], __ATOMIC_RELAXED, __HIP_MEMORY_SCOPE_AGENT);
        while (__all(v >= tt + 1) == 0) {
          __builtin_amdgcn_s_sleep(1);
          v = __hip_atomic_load(&myflags[l15], __ATOMIC_RELAXED, __HIP_MEMORY_SCOPE_AGENT);
        }
      }
      __syncthreads();  // release: o_out[t] fully published device-wide
    }
#pragma unroll
    for (int g2 = 0; g2 < 4; ++g2) pr[g2] = prn[g2];
    // keep weight fragments live across the step (discourage remat/sink)
#pragma unroll
    for (int ci = 0; ci < 2; ++ci)
#pragma unroll
      for (int kc = 0; kc < 8; ++kc) asm volatile("" : "+v"(swf[ci][kc]));
  }
}

// ---------------- launcher ----------------
static constexpr long long OFF_WT = 0;
static constexpr long long OFF_BIAS = 19660800;
static constexpr long long OFF_CAT = 19698944;
static constexpr long long OFF_EMB = 36476160;
static constexpr long long OFF_PRE = 44864768;
static constexpr long long OFF_O1 = 179082496;
static constexpr long long OFF_O2 = 212636928;
static constexpr long long OFF_SYNC = 246191360;
static constexpr long long SYNC_BYTES = 4096 + 131072;  // flags + zero slot
static constexpr long long OFF_FLAG = OFF_SYNC + SYNC_BYTES;

extern "C" void kernel_launch(void* const* d_in, const int* in_sizes, int n_in,
                              void* d_out, int out_size, void* d_ws, size_t ws_size,
                              hipStream_t stream) {
  char* ws = (char*)d_ws;
  u16* wt = (u16*)(ws + OFF_WT);
  float* biasp = (float*)(ws + OFF_BIAS);
  u16* cat = (u16*)(ws + OFF_CAT);
  u16* emb = (u16*)(ws + OFF_EMB);
  u16* pre0 = (u16*)(ws + OFF_PRE);
  u16* pre1 = pre0 + (long long)16384 * 2048;
  u16* o1 = (u16*)(ws + OFF_O1);
  u16* o2 = (u16*)(ws + OFF_O2);
  int* cnt1 = (int*)(ws + OFF_SYNC);
  int* cnt2 = cnt1 + 256;
  u16* zbuf = (u16*)(ws + OFF_SYNC + 4096);
  int* flag = (int*)(ws + OFF_FLAG);

  hipMemsetAsync(ws + OFF_SYNC, 0, SYNC_BYTES, stream);
  k_detect<<<1, 256, 0, stream>>>((const unsigned*)d_in[30], flag);

  WSegs wsg;
  const int widx[14] = {4, 5, 8, 9, 12, 13, 16, 17, 20, 21, 24, 25, 28, 30};
  const int wdst[15] = {0, 32768, 98304, 131072, 196608, 720896, 1769472, 2293760,
                        3342336, 5439488, 6488064, 8585216, 9633792, 9764864, 9816064};
  const int wn[15] = {32768, 65536, 32768, 65536, 524288, 1048576, 524288, 1048576,
                      2097152, 1048576, 2097152, 1048576, 131072, 51200, 14336};
  for (int j = 0; j < 14; ++j) { wsg.src[j] = d_in[widx[j]]; wsg.dst[j] = wdst[j]; wsg.n[j] = wn[j]; }
  wsg.src[14] = nullptr; wsg.dst[14] = wdst[14]; wsg.n[14] = wn[14];
  k_convw<<<1200, 256, 0, stream>>>(wsg, wt, flag);

  BSegs bsg;
  const int ba[8] = {6, 10, 14, 18, 22, 26, 29, 31};
  const int bb[8] = {7, 11, 15, 19, 23, 27, -1, -1};
  const int bdst[8] = {0, 512, 1024, 3072, 5120, 7168, 9216, 9472};
  const int bn_[8] = {512, 512, 2048, 2048, 2048, 2048, 256, 50};
  const int bnp[8] = {512, 512, 2048, 2048, 2048, 2048, 256, 64};
  for (int j = 0; j < 8; ++j) {
    bsg.a[j] = d_in[ba[j]];
    bsg.b[j] = (bb[j] >= 0) ? d_in[bb[j]] : nullptr;
    bsg.dst[j] = bdst[j]; bsg.n[j] = bn_[j]; bsg.np[j] = bnp[j];
  }
  k_convb<<<40, 256, 0, stream>>>(bsg, biasp, flag);

  k_wordgather<<<16384, 128, 0, stream>>>((const int*)d_in[0], d_in[2], cat, flag);
  k_char<<<dim3(256, 2), 256, 0, stream>>>((const int*)d_in[1], d_in[3],
                                           wt + 0, wt + 32768, wt + 98304, wt + 131072,
                                           biasp + 0, biasp + 512, cat, flag);
  k_gemm<64, 64, 1, 0><<<dim3(256, 4), 256, 0, stream>>>(cat, wt + 9633792, biasp + 9216, emb, 256, 512, 256, flag);
  k_gemm<128, 256, 0, 0><<<dim3(128, 8), 256, 0, stream>>>(emb, wt + 196608, biasp + 1024, pre0, 2048, 256, 2048, flag);
  k_gemm<128, 256, 0, 0><<<dim3(128, 8), 256, 0, stream>>>(emb, wt + 1769472, biasp + 3072, pre1, 2048, 256, 2048, flag);
  k_scan<<<dim3(16, 2), 512, 0, stream>>>(pre0, pre1, wt + 720896, wt + 2293760, o1, zbuf, cnt1);
  k_gemm<128, 256, 0, 0><<<dim3(128, 8), 256, 0, stream>>>(o1, wt + 3342336, biasp + 5120, pre0, 2048, 1024, 2048, flag);
  k_gemm<128, 256, 0, 0><<<dim3(128, 8), 256, 0, stream>>>(o1, wt + 6488064, biasp + 7168, pre1, 2048, 1024, 2048, flag);
  k_scan<<<dim3(16, 2), 512, 0, stream>>>(pre0, pre1, wt + 5439488, wt + 8585216, o2, zbuf, cnt2);
  k_gemm<64, 64, 2, 1><<<dim3(256, 1), 256, 0, stream>>>(o2, wt + 9764864, biasp + 9472, d_out, 50, 1024, 50, flag);
}

// Round 9
// 3500.822 us; speedup vs baseline: 2.7899x; 1.2256x over previous
//
// BiLSTM tagger — MI355X. Round 9: coalesce the h stage; kill flag false-sharing.
// Post-mortem R8: 6.8us/step still ~96% stall. Two defects: (1) stage loads
// were 64-line-per-instruction uncoalesced (lane stride 2KB); now flat-index
// remapped -> each wave reads 1KB contiguous per b128 (and LDS write is
// conflict-free, same-row consecutive). (2) all 16 flags shared one 64B MALL
// line (16 writers + 32 pollers ping-pong); now padded 128B apart, first
// check before s_sleep. Everything else unchanged from R8.
#include <hip/hip_runtime.h>

typedef unsigned short u16;
typedef unsigned long long ull;
typedef short short8 __attribute__((ext_vector_type(8)));
typedef float float4_ __attribute__((ext_vector_type(4)));
typedef short8 short8a __attribute__((may_alias));
typedef float4_ float4a __attribute__((may_alias));
typedef ull ulla __attribute__((may_alias));

#define MFMA16(a, b, c) __builtin_amdgcn_mfma_f32_16x16x32_bf16((a), (b), (c), 0, 0, 0)

static __device__ __forceinline__ float b2f(u16 v) { return __uint_as_float(((unsigned)v) << 16); }
static __device__ __forceinline__ u16 f2b(float f) {
  unsigned x = __float_as_uint(f);
  return (u16)((x + 0x7fffu + ((x >> 16) & 1u)) >> 16);
}
static __device__ __forceinline__ float ldv(const void* p, long long i, int isbf) {
  return isbf ? b2f(((const u16*)p)[i]) : ((const float*)p)[i];
}
static __device__ __forceinline__ float sigm(float x) { return 1.f / (1.f + __expf(-x)); }
static __device__ __forceinline__ float tanh_(float x) { return 1.f - 2.f / (__expf(2.f * x) + 1.f); }
static __device__ __forceinline__ float4_ splat4(float v) { float4_ r; r[0]=v; r[1]=v; r[2]=v; r[3]=v; return r; }

// ---------------- dtype detection (f32 vs bf16 input buffers) ----------------
__global__ __launch_bounds__(256) void k_detect(const unsigned* __restrict__ wtag, int* __restrict__ flag) {
  __shared__ int cs;
  if (threadIdx.x == 0) cs = 0;
  __syncthreads();
  int hits = 0;
  for (int i = threadIdx.x; i < 1024; i += 256) {
    unsigned b = (wtag[i] >> 8) & 0x7fu;
    hits += (b >= 0x36u && b <= 0x3fu) ? 1 : 0;
  }
  atomicAdd(&cs, hits);
  __syncthreads();
  if (threadIdx.x == 0) *flag = (cs > 512) ? 1 : 0;
}

// ---------------- weight conversion to bf16 workspace (x8 vectorized) ----------------
struct WSegs { const void* src[15]; int dst[15]; int n[15]; };
__global__ __launch_bounds__(256) void k_convw(WSegs s, u16* __restrict__ wt, const int* __restrict__ flagp) {
  const int isbf = *flagp;
  const long long total8 = 9830400 / 8;
  for (long long i8 = (long long)blockIdx.x * 256 + threadIdx.x; i8 < total8; i8 += (long long)gridDim.x * 256) {
    const long long i = i8 * 8;
    int k = 0;
#pragma unroll
    for (int j = 1; j < 15; ++j) if (i >= (long long)s.dst[j]) k = j;
    const long long loc = i - s.dst[k];
    short8 out;
    if (!s.src[k]) {
      for (int j = 0; j < 8; ++j) out[j] = 0;
    } else if (isbf) {
      out = *(const short8a*)((const u16*)s.src[k] + loc);
    } else {
      const float* fp = (const float*)s.src[k] + loc;
      const float4_ f0 = *(const float4a*)fp;
      const float4_ f1 = *(const float4a*)(fp + 4);
#pragma unroll
      for (int j = 0; j < 4; ++j) { out[j] = (short)f2b(f0[j]); out[j + 4] = (short)f2b(f1[j]); }
    }
    *(short8a*)(wt + i) = out;
  }
}

struct BSegs { const void* a[8]; const void* b[8]; int dst[8]; int n[8]; int np[8]; };
__global__ __launch_bounds__(256) void k_convb(BSegs s, float* __restrict__ bias, const int* __restrict__ flagp) {
  const int isbf = *flagp;
  for (int i = blockIdx.x * 256 + threadIdx.x; i < 9536; i += gridDim.x * 256) {
    int k = 0;
#pragma unroll
    for (int j = 1; j < 8; ++j) if (i >= s.dst[j]) k = j;
    const int loc = i - s.dst[k];
    float v = 0.f;
    if (loc < s.n[k]) {
      v = ldv(s.a[k], loc, isbf);
      if (s.b[k]) v += ldv(s.b[k], loc, isbf);
    }
    bias[i] = v;
  }
}

// ---------------- word embedding gather into cat[:,0:256] ----------------
__global__ __launch_bounds__(128) void k_wordgather(const int* __restrict__ sent, const void* __restrict__ wemb,
                                                    u16* __restrict__ cat, const int* __restrict__ flagp) {
  const int n = blockIdx.x;
  const int idx = sent[n];
  const int isbf = *flagp;
  for (int d = threadIdx.x; d < 256; d += 128)
    cat[(long long)n * 512 + d] = f2b(ldv(wemb, (long long)idx * 256 + d, isbf));
}

// ---------------- char biLSTM: 64 seqs/block, 16 steps, D=64 H=128 ----------------
__global__ __launch_bounds__(256) void k_char(const int* __restrict__ cs, const void* __restrict__ wchar,
                                              const u16* __restrict__ wihF, const u16* __restrict__ whhF,
                                              const u16* __restrict__ wihB, const u16* __restrict__ whhB,
                                              const float* __restrict__ biasF, const float* __restrict__ biasB,
                                              u16* __restrict__ cat, const int* __restrict__ flagp) {
  const int dir = blockIdx.y;
  const int nb = blockIdx.x;
  const u16* wih = dir ? wihB : wihF;
  const u16* whh = dir ? whhB : whhF;
  const float* bias = dir ? biasB : biasF;
  const int isbf = *flagp;
  __shared__ __align__(16) u16 xs[64][72];
  __shared__ __align__(16) u16 hs[64][136];
  const int tid = threadIdx.x, wv = tid >> 6, lane = tid & 63;
  for (int i = tid; i < 64 * 136; i += 256) ((u16*)hs)[i] = 0;
  float c[2][4][4];
#pragma unroll
  for (int a1 = 0; a1 < 2; ++a1)
#pragma unroll
    for (int a2 = 0; a2 < 4; ++a2)
#pragma unroll
      for (int a3 = 0; a3 < 4; ++a3) c[a1][a2][a3] = 0.f;

  for (int tt = 0; tt < 16; ++tt) {
    const int t = dir ? (15 - tt) : tt;
    {
      const int sid = tid >> 2, part = tid & 3;
      const int n = nb * 64 + sid;
      const int idx = cs[n * 16 + t];
#pragma unroll
      for (int q = 0; q < 16; ++q) {
        const int d2 = part * 16 + q;
        float v = 0.f;
        if (idx != 0) v = ldv(wchar, (long long)idx * 64 + d2, isbf);
        xs[sid][d2] = f2b(v);
      }
    }
    __syncthreads();
    float4_ acc[2][4][4];
#pragma unroll
    for (int ut = 0; ut < 2; ++ut)
#pragma unroll
      for (int g = 0; g < 4; ++g) {
        const float bv = bias[g * 128 + (wv + 4 * ut) * 16 + (lane & 15)];
#pragma unroll
        for (int rt = 0; rt < 4; ++rt) acc[ut][g][rt] = splat4(bv);
      }
#pragma unroll
    for (int kc = 0; kc < 6; ++kc) {
      short8 a[4];
      if (kc < 2) {
#pragma unroll
        for (int rt = 0; rt < 4; ++rt)
          a[rt] = *(const short8a*)&xs[rt * 16 + (lane & 15)][kc * 32 + (lane >> 4) * 8];
      } else {
#pragma unroll
        for (int rt = 0; rt < 4; ++rt)
          a[rt] = *(const short8a*)&hs[rt * 16 + (lane & 15)][(kc - 2) * 32 + (lane >> 4) * 8];
      }
#pragma unroll
      for (int ut = 0; ut < 2; ++ut)
#pragma unroll
        for (int g = 0; g < 4; ++g) {
          const int col = g * 128 + (wv + 4 * ut) * 16 + (lane & 15);
          short8 bfr;
          if (kc < 2) bfr = *(const short8a*)(wih + col * 64 + kc * 32 + (lane >> 4) * 8);
          else        bfr = *(const short8a*)(whh + col * 128 + (kc - 2) * 32 + (lane >> 4) * 8);
#pragma unroll
          for (int rt = 0; rt < 4; ++rt) acc[ut][g][rt] = MFMA16(a[rt], bfr, acc[ut][g][rt]);
        }
    }
    __syncthreads();
#pragma unroll
    for (int ut = 0; ut < 2; ++ut)
#pragma unroll
      for (int rt = 0; rt < 4; ++rt)
#pragma unroll
        for (int r = 0; r < 4; ++r) {
          const float iv = acc[ut][0][rt][r];
          const float fv = acc[ut][1][rt][r];
          const float gv = acc[ut][2][rt][r];
          const float ov = acc[ut][3][rt][r];
          float& cc = c[ut][rt][r];
          cc = sigm(fv) * cc + sigm(iv) * tanh_(gv);
          const float h = sigm(ov) * tanh_(cc);
          const int seq = rt * 16 + (lane >> 4) * 4 + r;
          const int u = (wv + 4 * ut) * 16 + (lane & 15);
          const u16 hv = f2b(h);
          hs[seq][u] = hv;
          if (tt == 15) cat[(long long)(nb * 64 + seq) * 512 + 256 + dir * 128 + u] = hv;
        }
  }
}

// ---------------- generic MFMA GEMM ----------------
template <int TM, int TN, int PERM, int OUTM>
__global__ __launch_bounds__(256) void k_gemm(const u16* __restrict__ A, const u16* __restrict__ Wt,
                                              const float* __restrict__ bias, void* __restrict__ Cout,
                                              const int N, const int K, const int ldc,
                                              const int* __restrict__ flagp) {
  constexpr int RT = TM / 16;
  constexpr int CPW = TN / 64;
  const int bm = blockIdx.x, bn = blockIdx.y;
  const int tid = threadIdx.x, wv = tid >> 6, lane = tid & 63;
  __shared__ __align__(16) u16 As[TM][72];
  float4_ acc[CPW][RT];
#pragma unroll
  for (int ci = 0; ci < CPW; ++ci)
#pragma unroll
    for (int rt = 0; rt < RT; ++rt) acc[ci][rt] = splat4(0.f);
  const int nk = K >> 6;
  for (int kc = 0; kc < nk; ++kc) {
    __syncthreads();
    for (int idx = tid; idx < TM * 4; idx += 256) {
      const int r = idx >> 2, sg = idx & 3;
      const u16* src = A + (long long)(bm * TM + r) * K + kc * 64 + sg * 16;
      *(short8a*)&As[r][sg * 16] = *(const short8a*)src;
      *(short8a*)&As[r][sg * 16 + 8] = *(const short8a*)(src + 8);
    }
    __syncthreads();
#pragma unroll
    for (int kk = 0; kk < 2; ++kk) {
      short8 af[RT];
#pragma unroll
      for (int rt = 0; rt < RT; ++rt)
        af[rt] = *(const short8a*)&As[rt * 16 + (lane & 15)][kk * 32 + (lane >> 4) * 8];
#pragma unroll
      for (int ci = 0; ci < CPW; ++ci) {
        const int ct = wv + ci * 4;
        const short8 bf = *(const short8a*)(Wt + (long long)(bn * TN + ct * 16 + (lane & 15)) * K +
                                            kc * 64 + kk * 32 + (lane >> 4) * 8);
#pragma unroll
        for (int rt = 0; rt < RT; ++rt) acc[ci][rt] = MFMA16(af[rt], bf, acc[ci][rt]);
      }
    }
  }
  const int isbf = (OUTM == 1) ? *flagp : 0;
#pragma unroll
  for (int ci = 0; ci < CPW; ++ci)
#pragma unroll
    for (int rt = 0; rt < RT; ++rt)
#pragma unroll
      for (int r = 0; r < 4; ++r) {
        const int row = bm * TM + rt * 16 + (lane >> 4) * 4 + r;
        const int col = bn * TN + (wv + ci * 4) * 16 + (lane & 15);
        if (col < N) {
          const float v = acc[ci][rt][r] + bias[col];
          long long orow;
          if (PERM == 0) orow = row;
          else if (PERM == 1) orow = (long long)(row & 255) * 64 + (row >> 8);
          else orow = (long long)(row & 63) * 256 + (row >> 6);
          if (OUTM == 0) ((u16*)Cout)[orow * ldc + col] = f2b(v);
          else if (isbf) ((u16*)Cout)[orow * ldc + col] = f2b(v);
          else ((float*)Cout)[orow * ldc + col] = v;
        }
      }
}

// ---------------- persistent LSTM scan (one layer, both dirs) ----------------
// grid (16, 2=dir), 512 threads (8 waves = gate g x K-half kh). h ring =
// o_out: publish = ONE sc1 u64/thread; consume = plain coalesced b128 loads
// (first-touch ring lines can't be stale) -> swizzled LDS. Flags padded 128B.
__global__ __launch_bounds__(512, 1) void k_scan(const u16* __restrict__ pre0, const u16* __restrict__ pre1,
                                                 const u16* __restrict__ whh0, const u16* __restrict__ whh1,
                                                 u16* __restrict__ o_out, const u16* __restrict__ zbuf,
                                                 int* __restrict__ flags) {
  const int dir = blockIdx.y, blk = blockIdx.x;
  const u16* __restrict__ pre = dir ? pre1 : pre0;
  const u16* __restrict__ whh = dir ? whh1 : whh0;
  int* myflags = flags + dir * 512;   // 16 flags, 32-int (128B) stride
  const int u0 = blk * 32;
  __shared__ __align__(16) u16 hstage[64 * 512];    // 64KB, XOR-swizzled rows
  __shared__ __align__(16) float xch[8 * 64 * 36];  // 72KB [kh*4+g][b][36pad]
  const int tid = threadIdx.x, lane = tid & 63;
  const int wv = tid >> 6;
  const int l15 = lane & 15, q = lane >> 4;
  const int g = wv & 3, kh = wv >> 2;

  // weight fragments: rows u0 + ci*16 + l15 of gate g, k = kh*256 + kc*32 + q*8
  float4_ swf[2][8];
#pragma unroll
  for (int ci = 0; ci < 2; ++ci)
#pragma unroll
    for (int kc = 0; kc < 8; ++kc)
      swf[ci][kc] = *(const float4a*)(whh + (long long)(g * 512 + u0 + ci * 16 + l15) * 512 +
                                      kh * 256 + kc * 32 + q * 8);

  // activation ownership: batch bb, unit quad u0+uu .. +4
  const int bb = tid >> 3;
  const int uu = (tid & 7) * 4;
  float c4[4];
#pragma unroll
  for (int j = 0; j < 4; ++j) c4[j] = 0.f;

  ull pr[4], prn[4];
  {
    const int t0 = dir ? 255 : 0;
    const u16* pb = pre + (long long)(t0 * 64 + bb) * 2048 + u0 + uu;
#pragma unroll
    for (int g2 = 0; g2 < 4; ++g2) pr[g2] = *(const ulla*)(pb + g2 * 512);
  }

  for (int tt = 0; tt < 256; ++tt) {
    const int t = dir ? (255 - tt) : tt;

    // ---- stage h_{t-1}: fully coalesced (per-wave 1KB contiguous per b128) ----
    {
      const u16* base;
      if (tt == 0) {
        base = zbuf + dir * 512;
      } else {
        const int tp = dir ? (t + 1) : (t - 1);
        base = o_out + (long long)tp * 65536 + dir * 512;
      }
      const int row0 = wv;           // wave w, iter it -> row = w + it*8
      const int off = lane * 8;      // u16 offset within 512-wide dir-half
#pragma unroll
      for (int it = 0; it < 8; ++it) {
        const int row = row0 + it * 8;
        const float4_ v = *(const float4a*)(base + (long long)row * 1024 + off);
        *(float4a*)((char*)hstage + row * 1024 + ((off * 2) ^ ((row & 7) << 4))) = v;
      }
    }
    __syncthreads();

    // ---- MFMA: acc[ci][bt] over this wave's (gate, K-half) ----
    float4_ acc[2][4];
#pragma unroll
    for (int ci = 0; ci < 2; ++ci)
#pragma unroll
      for (int bt = 0; bt < 4; ++bt) acc[ci][bt] = splat4(0.f);
    const char* hsb = (const char*)hstage;
#pragma unroll
    for (int kc = 0; kc < 8; ++kc) {
      const short8 w0 = __builtin_bit_cast(short8, swf[0][kc]);
      const short8 w1 = __builtin_bit_cast(short8, swf[1][kc]);
#pragma unroll
      for (int bt = 0; bt < 4; ++bt) {
        const int row = bt * 16 + l15;
        const short8 A = *(const short8a*)(hsb + row * 1024 +
                          ((kh * 512 + kc * 64 + q * 16) ^ ((row & 7) << 4)));
        acc[0][bt] = MFMA16(w0, A, acc[0][bt]);
        acc[1][bt] = MFMA16(w1, A, acc[1][bt]);
      }
    }

    // ---- exchange K-half partials ([krow][b][36pad], <=2-way both sides) ----
#pragma unroll
    for (int ci = 0; ci < 2; ++ci)
#pragma unroll
      for (int bt = 0; bt < 4; ++bt)
        *(float4a*)&xch[((kh * 4 + g) * 64 + bt * 16 + l15) * 36 + ci * 16 + q * 4] = acc[ci][bt];
    __syncthreads();

    // ---- activation: 4 outputs (batch bb, units u0+uu..+3) ----
    float4_ gv[4];
#pragma unroll
    for (int g2 = 0; g2 < 4; ++g2) {
      const float4_ p0 = *(const float4a*)&xch[(g2 * 64 + bb) * 36 + uu];
      const float4_ p1 = *(const float4a*)&xch[((4 + g2) * 64 + bb) * 36 + uu];
      gv[g2] = p0 + p1;
    }
    ull hv = 0;
#pragma unroll
    for (int j = 0; j < 4; ++j) {
      const float iv = gv[0][j] + b2f((u16)(pr[0] >> (16 * j)));
      const float fv = gv[1][j] + b2f((u16)(pr[1] >> (16 * j)));
      const float gg = gv[2][j] + b2f((u16)(pr[2] >> (16 * j)));
      const float ov = gv[3][j] + b2f((u16)(pr[3] >> (16 * j)));
      c4[j] = sigm(fv) * c4[j] + sigm(iv) * tanh_(gg);
      const float h = sigm(ov) * tanh_(c4[j]);
      hv |= (ull)f2b(h) << (16 * j);
    }
    // single write-through publish into the ring (= o_out)
    __hip_atomic_store((ull*)(o_out + (long long)(t * 64 + bb) * 1024 + dir * 512 + u0 + uu), hv,
                       __ATOMIC_RELAXED, __HIP_MEMORY_SCOPE_AGENT);
    asm volatile("s_waitcnt vmcnt(0)" ::: "memory");  // h at coherence point
    __syncthreads();
    if (tid == 0)
      __hip_atomic_store(&myflags[blk * 32], tt + 1, __ATOMIC_RELAXED, __HIP_MEMORY_SCOPE_AGENT);
    // overlap poll: next-step pre prefetch
    {
      const int ttn = (tt < 255) ? tt + 1 : tt;
      const int tn = dir ? (255 - ttn) : ttn;
      const u16* pb = pre + (long long)(tn * 64 + bb) * 2048 + u0 + uu;
#pragma unroll
      for (int g2 = 0; g2 < 4; ++g2) prn[g2] = *(const ulla*)(pb + g2 * 512);
    }
    if (tt != 255) {
      if (wv == 0) {
        const int* fp = myflags + (l15) * 32;
        int v = __hip_atomic_load(fp, __ATOMIC_RELAXED, __HIP_MEMORY_SCOPE_AGENT);
        while (__all(v >= tt + 1) == 0) {
          __builtin_amdgcn_s_sleep(1);
          v = __hip_atomic_load(fp, __ATOMIC_RELAXED, __HIP_MEMORY_SCOPE_AGENT);
        }
      }
      __syncthreads();  // release: o_out[t] fully published device-wide
    }
#pragma unroll
    for (int g2 = 0; g2 < 4; ++g2) pr[g2] = prn[g2];
    // keep weight fragments live across the step (discourage remat/sink)
#pragma unroll
    for (int ci = 0; ci < 2; ++ci)
#pragma unroll
      for (int kc = 0; kc < 8; ++kc) asm volatile("" : "+v"(swf[ci][kc]));
  }
}

// ---------------- launcher ----------------
static constexpr long long OFF_WT = 0;
static constexpr long long OFF_BIAS = 19660800;
static constexpr long long OFF_CAT = 19698944;
static constexpr long long OFF_EMB = 36476160;
static constexpr long long OFF_PRE = 44864768;
static constexpr long long OFF_O1 = 179082496;
static constexpr long long OFF_O2 = 212636928;
static constexpr long long OFF_SYNC = 246191360;
static constexpr long long SYNC_BYTES = 16384 + 131072;  // padded flags + zero slot
static constexpr long long OFF_FLAG = OFF_SYNC + SYNC_BYTES;

extern "C" void kernel_launch(void* const* d_in, const int* in_sizes, int n_in,
                              void* d_out, int out_size, void* d_ws, size_t ws_size,
                              hipStream_t stream) {
  char* ws = (char*)d_ws;
  u16* wt = (u16*)(ws + OFF_WT);
  float* biasp = (float*)(ws + OFF_BIAS);
  u16* cat = (u16*)(ws + OFF_CAT);
  u16* emb = (u16*)(ws + OFF_EMB);
  u16* pre0 = (u16*)(ws + OFF_PRE);
  u16* pre1 = pre0 + (long long)16384 * 2048;
  u16* o1 = (u16*)(ws + OFF_O1);
  u16* o2 = (u16*)(ws + OFF_O2);
  int* cnt1 = (int*)(ws + OFF_SYNC);          // 2 dirs x 16 flags x 32-int stride
  int* cnt2 = cnt1 + 1024;
  u16* zbuf = (u16*)(ws + OFF_SYNC + 16384);  // 128KB zero slot
  int* flag = (int*)(ws + OFF_FLAG);

  hipMemsetAsync(ws + OFF_SYNC, 0, SYNC_BYTES, stream);
  k_detect<<<1, 256, 0, stream>>>((const unsigned*)d_in[30], flag);

  WSegs wsg;
  const int widx[14] = {4, 5, 8, 9, 12, 13, 16, 17, 20, 21, 24, 25, 28, 30};
  const int wdst[15] = {0, 32768, 98304, 131072, 196608, 720896, 1769472, 2293760,
                        3342336, 5439488, 6488064, 8585216, 9633792, 9764864, 9816064};
  const int wn[15] = {32768, 65536, 32768, 65536, 524288, 1048576, 524288, 1048576,
                      2097152, 1048576, 2097152, 1048576, 131072, 51200, 14336};
  for (int j = 0; j < 14; ++j) { wsg.src[j] = d_in[widx[j]]; wsg.dst[j] = wdst[j]; wsg.n[j] = wn[j]; }
  wsg.src[14] = nullptr; wsg.dst[14] = wdst[14]; wsg.n[14] = wn[14];
  k_convw<<<1200, 256, 0, stream>>>(wsg, wt, flag);

  BSegs bsg;
  const int ba[8] = {6, 10, 14, 18, 22, 26, 29, 31};
  const int bb[8] = {7, 11, 15, 19, 23, 27, -1, -1};
  const int bdst[8] = {0, 512, 1024, 3072, 5120, 7168, 9216, 9472};
  const int bn_[8] = {512, 512, 2048, 2048, 2048, 2048, 256, 50};
  const int bnp[8] = {512, 512, 2048, 2048, 2048, 2048, 256, 64};
  for (int j = 0; j < 8; ++j) {
    bsg.a[j] = d_in[ba[j]];
    bsg.b[j] = (bb[j] >= 0) ? d_in[bb[j]] : nullptr;
    bsg.dst[j] = bdst[j]; bsg.n[j] = bn_[j]; bsg.np[j] = bnp[j];
  }
  k_convb<<<40, 256, 0, stream>>>(bsg, biasp, flag);

  k_wordgather<<<16384, 128, 0, stream>>>((const int*)d_in[0], d_in[2], cat, flag);
  k_char<<<dim3(256, 2), 256, 0, stream>>>((const int*)d_in[1], d_in[3],
                                           wt + 0, wt + 32768, wt + 98304, wt + 131072,
                                           biasp + 0, biasp + 512, cat, flag);
  k_gemm<64, 64, 1, 0><<<dim3(256, 4), 256, 0, stream>>>(cat, wt + 9633792, biasp + 9216, emb, 256, 512, 256, flag);
  k_gemm<128, 256, 0, 0><<<dim3(128, 8), 256, 0, stream>>>(emb, wt + 196608, biasp + 1024, pre0, 2048, 256, 2048, flag);
  k_gemm<128, 256, 0, 0><<<dim3(128, 8), 256, 0, stream>>>(emb, wt + 1769472, biasp + 3072, pre1, 2048, 256, 2048, flag);
  k_scan<<<dim3(16, 2), 512, 0, stream>>>(pre0, pre1, wt + 720896, wt + 2293760, o1, zbuf, cnt1);
  k_gemm<128, 256, 0, 0><<<dim3(128, 8), 256, 0, stream>>>(o1, wt + 3342336, biasp + 5120, pre0, 2048, 1024, 2048, flag);
  k_gemm<128, 256, 0, 0><<<dim3(128, 8), 256, 0, stream>>>(o1, wt + 6488064, biasp + 7168, pre1, 2048, 1024, 2048, flag);
  k_scan<<<dim3(16, 2), 512, 0, stream>>>(pre0, pre1, wt + 5439488, wt + 8585216, o2, zbuf, cnt2);
  k_gemm<64, 64, 2, 1><<<dim3(256, 1), 256, 0, stream>>>(o2, wt + 9764864, biasp + 9472, d_out, 50, 1024, 50, flag);
}

// Round 10
// 3433.750 us; speedup vs baseline: 2.8444x; 1.0195x over previous
//
// BiLSTM tagger — MI355X. Round 10: conflict-free exchange + all-wave poll.
// Post-mortem R9: xch read bank = 4*((bb+t)%8) -> 8-way conflict (1281
// cyc/block-step, the 1.05e7 counter). New xch [8][64][32] f32 with XOR
// swizzle colblk^=batch&7 — derived conflict-free on BOTH write and read.
// Handshake: all 8 waves poll the padded flags (not wave0+barrier) and fall
// straight into their stage share; release barrier dropped (3 barriers/step).
#include <hip/hip_runtime.h>

typedef unsigned short u16;
typedef unsigned long long ull;
typedef short short8 __attribute__((ext_vector_type(8)));
typedef float float4_ __attribute__((ext_vector_type(4)));
typedef short8 short8a __attribute__((may_alias));
typedef float4_ float4a __attribute__((may_alias));
typedef ull ulla __attribute__((may_alias));

#define MFMA16(a, b, c) __builtin_amdgcn_mfma_f32_16x16x32_bf16((a), (b), (c), 0, 0, 0)

static __device__ __forceinline__ float b2f(u16 v) { return __uint_as_float(((unsigned)v) << 16); }
static __device__ __forceinline__ u16 f2b(float f) {
  unsigned x = __float_as_uint(f);
  return (u16)((x + 0x7fffu + ((x >> 16) & 1u)) >> 16);
}
static __device__ __forceinline__ float ldv(const void* p, long long i, int isbf) {
  return isbf ? b2f(((const u16*)p)[i]) : ((const float*)p)[i];
}
static __device__ __forceinline__ float sigm(float x) { return 1.f / (1.f + __expf(-x)); }
static __device__ __forceinline__ float tanh_(float x) { return 1.f - 2.f / (__expf(2.f * x) + 1.f); }
static __device__ __forceinline__ float4_ splat4(float v) { float4_ r; r[0]=v; r[1]=v; r[2]=v; r[3]=v; return r; }

// ---------------- dtype detection (f32 vs bf16 input buffers) ----------------
__global__ __launch_bounds__(256) void k_detect(const unsigned* __restrict__ wtag, int* __restrict__ flag) {
  __shared__ int cs;
  if (threadIdx.x == 0) cs = 0;
  __syncthreads();
  int hits = 0;
  for (int i = threadIdx.x; i < 1024; i += 256) {
    unsigned b = (wtag[i] >> 8) & 0x7fu;
    hits += (b >= 0x36u && b <= 0x3fu) ? 1 : 0;
  }
  atomicAdd(&cs, hits);
  __syncthreads();
  if (threadIdx.x == 0) *flag = (cs > 512) ? 1 : 0;
}

// ---------------- weight conversion to bf16 workspace (x8 vectorized) ----------------
struct WSegs { const void* src[15]; int dst[15]; int n[15]; };
__global__ __launch_bounds__(256) void k_convw(WSegs s, u16* __restrict__ wt, const int* __restrict__ flagp) {
  const int isbf = *flagp;
  const long long total8 = 9830400 / 8;
  for (long long i8 = (long long)blockIdx.x * 256 + threadIdx.x; i8 < total8; i8 += (long long)gridDim.x * 256) {
    const long long i = i8 * 8;
    int k = 0;
#pragma unroll
    for (int j = 1; j < 15; ++j) if (i >= (long long)s.dst[j]) k = j;
    const long long loc = i - s.dst[k];
    short8 out;
    if (!s.src[k]) {
      for (int j = 0; j < 8; ++j) out[j] = 0;
    } else if (isbf) {
      out = *(const short8a*)((const u16*)s.src[k] + loc);
    } else {
      const float* fp = (const float*)s.src[k] + loc;
      const float4_ f0 = *(const float4a*)fp;
      const float4_ f1 = *(const float4a*)(fp + 4);
#pragma unroll
      for (int j = 0; j < 4; ++j) { out[j] = (short)f2b(f0[j]); out[j + 4] = (short)f2b(f1[j]); }
    }
    *(short8a*)(wt + i) = out;
  }
}

struct BSegs { const void* a[8]; const void* b[8]; int dst[8]; int n[8]; int np[8]; };
__global__ __launch_bounds__(256) void k_convb(BSegs s, float* __restrict__ bias, const int* __restrict__ flagp) {
  const int isbf = *flagp;
  for (int i = blockIdx.x * 256 + threadIdx.x; i < 9536; i += gridDim.x * 256) {
    int k = 0;
#pragma unroll
    for (int j = 1; j < 8; ++j) if (i >= s.dst[j]) k = j;
    const int loc = i - s.dst[k];
    float v = 0.f;
    if (loc < s.n[k]) {
      v = ldv(s.a[k], loc, isbf);
      if (s.b[k]) v += ldv(s.b[k], loc, isbf);
    }
    bias[i] = v;
  }
}

// ---------------- word embedding gather into cat[:,0:256] ----------------
__global__ __launch_bounds__(128) void k_wordgather(const int* __restrict__ sent, const void* __restrict__ wemb,
                                                    u16* __restrict__ cat, const int* __restrict__ flagp) {
  const int n = blockIdx.x;
  const int idx = sent[n];
  const int isbf = *flagp;
  for (int d = threadIdx.x; d < 256; d += 128)
    cat[(long long)n * 512 + d] = f2b(ldv(wemb, (long long)idx * 256 + d, isbf));
}

// ---------------- char biLSTM: 64 seqs/block, 16 steps, D=64 H=128 ----------------
__global__ __launch_bounds__(256) void k_char(const int* __restrict__ cs, const void* __restrict__ wchar,
                                              const u16* __restrict__ wihF, const u16* __restrict__ whhF,
                                              const u16* __restrict__ wihB, const u16* __restrict__ whhB,
                                              const float* __restrict__ biasF, const float* __restrict__ biasB,
                                              u16* __restrict__ cat, const int* __restrict__ flagp) {
  const int dir = blockIdx.y;
  const int nb = blockIdx.x;
  const u16* wih = dir ? wihB : wihF;
  const u16* whh = dir ? whhB : whhF;
  const float* bias = dir ? biasB : biasF;
  const int isbf = *flagp;
  __shared__ __align__(16) u16 xs[64][72];
  __shared__ __align__(16) u16 hs[64][136];
  const int tid = threadIdx.x, wv = tid >> 6, lane = tid & 63;
  for (int i = tid; i < 64 * 136; i += 256) ((u16*)hs)[i] = 0;
  float c[2][4][4];
#pragma unroll
  for (int a1 = 0; a1 < 2; ++a1)
#pragma unroll
    for (int a2 = 0; a2 < 4; ++a2)
#pragma unroll
      for (int a3 = 0; a3 < 4; ++a3) c[a1][a2][a3] = 0.f;

  for (int tt = 0; tt < 16; ++tt) {
    const int t = dir ? (15 - tt) : tt;
    {
      const int sid = tid >> 2, part = tid & 3;
      const int n = nb * 64 + sid;
      const int idx = cs[n * 16 + t];
#pragma unroll
      for (int q = 0; q < 16; ++q) {
        const int d2 = part * 16 + q;
        float v = 0.f;
        if (idx != 0) v = ldv(wchar, (long long)idx * 64 + d2, isbf);
        xs[sid][d2] = f2b(v);
      }
    }
    __syncthreads();
    float4_ acc[2][4][4];
#pragma unroll
    for (int ut = 0; ut < 2; ++ut)
#pragma unroll
      for (int g = 0; g < 4; ++g) {
        const float bv = bias[g * 128 + (wv + 4 * ut) * 16 + (lane & 15)];
#pragma unroll
        for (int rt = 0; rt < 4; ++rt) acc[ut][g][rt] = splat4(bv);
      }
#pragma unroll
    for (int kc = 0; kc < 6; ++kc) {
      short8 a[4];
      if (kc < 2) {
#pragma unroll
        for (int rt = 0; rt < 4; ++rt)
          a[rt] = *(const short8a*)&xs[rt * 16 + (lane & 15)][kc * 32 + (lane >> 4) * 8];
      } else {
#pragma unroll
        for (int rt = 0; rt < 4; ++rt)
          a[rt] = *(const short8a*)&hs[rt * 16 + (lane & 15)][(kc - 2) * 32 + (lane >> 4) * 8];
      }
#pragma unroll
      for (int ut = 0; ut < 2; ++ut)
#pragma unroll
        for (int g = 0; g < 4; ++g) {
          const int col = g * 128 + (wv + 4 * ut) * 16 + (lane & 15);
          short8 bfr;
          if (kc < 2) bfr = *(const short8a*)(wih + col * 64 + kc * 32 + (lane >> 4) * 8);
          else        bfr = *(const short8a*)(whh + col * 128 + (kc - 2) * 32 + (lane >> 4) * 8);
#pragma unroll
          for (int rt = 0; rt < 4; ++rt) acc[ut][g][rt] = MFMA16(a[rt], bfr, acc[ut][g][rt]);
        }
    }
    __syncthreads();
#pragma unroll
    for (int ut = 0; ut < 2; ++ut)
#pragma unroll
      for (int rt = 0; rt < 4; ++rt)
#pragma unroll
        for (int r = 0; r < 4; ++r) {
          const float iv = acc[ut][0][rt][r];
          const float fv = acc[ut][1][rt][r];
          const float gv = acc[ut][2][rt][r];
          const float ov = acc[ut][3][rt][r];
          float& cc = c[ut][rt][r];
          cc = sigm(fv) * cc + sigm(iv) * tanh_(gv);
          const float h = sigm(ov) * tanh_(cc);
          const int seq = rt * 16 + (lane >> 4) * 4 + r;
          const int u = (wv + 4 * ut) * 16 + (lane & 15);
          const u16 hv = f2b(h);
          hs[seq][u] = hv;
          if (tt == 15) cat[(long long)(nb * 64 + seq) * 512 + 256 + dir * 128 + u] = hv;
        }
  }
}

// ---------------- generic MFMA GEMM ----------------
template <int TM, int TN, int PERM, int OUTM>
__global__ __launch_bounds__(256) void k_gemm(const u16* __restrict__ A, const u16* __restrict__ Wt,
                                              const float* __restrict__ bias, void* __restrict__ Cout,
                                              const int N, const int K, const int ldc,
                                              const int* __restrict__ flagp) {
  constexpr int RT = TM / 16;
  constexpr int CPW = TN / 64;
  const int bm = blockIdx.x, bn = blockIdx.y;
  const int tid = threadIdx.x, wv = tid >> 6, lane = tid & 63;
  __shared__ __align__(16) u16 As[TM][72];
  float4_ acc[CPW][RT];
#pragma unroll
  for (int ci = 0; ci < CPW; ++ci)
#pragma unroll
    for (int rt = 0; rt < RT; ++rt) acc[ci][rt] = splat4(0.f);
  const int nk = K >> 6;
  for (int kc = 0; kc < nk; ++kc) {
    __syncthreads();
    for (int idx = tid; idx < TM * 4; idx += 256) {
      const int r = idx >> 2, sg = idx & 3;
      const u16* src = A + (long long)(bm * TM + r) * K + kc * 64 + sg * 16;
      *(short8a*)&As[r][sg * 16] = *(const short8a*)src;
      *(short8a*)&As[r][sg * 16 + 8] = *(const short8a*)(src + 8);
    }
    __syncthreads();
#pragma unroll
    for (int kk = 0; kk < 2; ++kk) {
      short8 af[RT];
#pragma unroll
      for (int rt = 0; rt < RT; ++rt)
        af[rt] = *(const short8a*)&As[rt * 16 + (lane & 15)][kk * 32 + (lane >> 4) * 8];
#pragma unroll
      for (int ci = 0; ci < CPW; ++ci) {
        const int ct = wv + ci * 4;
        const short8 bf = *(const short8a*)(Wt + (long long)(bn * TN + ct * 16 + (lane & 15)) * K +
                                            kc * 64 + kk * 32 + (lane >> 4) * 8);
#pragma unroll
        for (int rt = 0; rt < RT; ++rt) acc[ci][rt] = MFMA16(af[rt], bf, acc[ci][rt]);
      }
    }
  }
  const int isbf = (OUTM == 1) ? *flagp : 0;
#pragma unroll
  for (int ci = 0; ci < CPW; ++ci)
#pragma unroll
    for (int rt = 0; rt < RT; ++rt)
#pragma unroll
      for (int r = 0; r < 4; ++r) {
        const int row = bm * TM + rt * 16 + (lane >> 4) * 4 + r;
        const int col = bn * TN + (wv + ci * 4) * 16 + (lane & 15);
        if (col < N) {
          const float v = acc[ci][rt][r] + bias[col];
          long long orow;
          if (PERM == 0) orow = row;
          else if (PERM == 1) orow = (long long)(row & 255) * 64 + (row >> 8);
          else orow = (long long)(row & 63) * 256 + (row >> 6);
          if (OUTM == 0) ((u16*)Cout)[orow * ldc + col] = f2b(v);
          else if (isbf) ((u16*)Cout)[orow * ldc + col] = f2b(v);
          else ((float*)Cout)[orow * ldc + col] = v;
        }
      }
}

// ---------------- persistent LSTM scan (one layer, both dirs) ----------------
// grid (16, 2=dir), 512 threads (8 waves = gate g x K-half kh). h ring = o_out
// (publish ONE sc1 u64/thread; consume plain coalesced b128). Exchange
// [8][64][32] f32 with colblk^=(batch&7) XOR swizzle (conflict-free both
// sides). All-wave flag poll; 3 barriers/step.
__global__ __launch_bounds__(512, 1) void k_scan(const u16* __restrict__ pre0, const u16* __restrict__ pre1,
                                                 const u16* __restrict__ whh0, const u16* __restrict__ whh1,
                                                 u16* __restrict__ o_out, const u16* __restrict__ zbuf,
                                                 int* __restrict__ flags) {
  const int dir = blockIdx.y, blk = blockIdx.x;
  const u16* __restrict__ pre = dir ? pre1 : pre0;
  const u16* __restrict__ whh = dir ? whh1 : whh0;
  int* myflags = flags + dir * 512;   // 16 flags, 32-int (128B) stride
  const int u0 = blk * 32;
  __shared__ __align__(16) u16 hstage[64 * 512];    // 64KB, XOR-swizzled rows
  __shared__ __align__(16) float xch[8 * 64 * 32];  // 64KB [kh*4+g][b][quad^b&7]
  const int tid = threadIdx.x, lane = tid & 63;
  const int wv = tid >> 6;
  const int l15 = lane & 15, q = lane >> 4;
  const int g = wv & 3, kh = wv >> 2;

  // weight fragments: rows u0 + ci*16 + l15 of gate g, k = kh*256 + kc*32 + q*8
  float4_ swf[2][8];
#pragma unroll
  for (int ci = 0; ci < 2; ++ci)
#pragma unroll
    for (int kc = 0; kc < 8; ++kc)
      swf[ci][kc] = *(const float4a*)(whh + (long long)(g * 512 + u0 + ci * 16 + l15) * 512 +
                                      kh * 256 + kc * 32 + q * 8);

  // activation ownership: batch bb, unit quad t8 (units u0 + t8*4 .. +4)
  const int bb = tid >> 3;
  const int t8 = tid & 7;
  float c4[4];
#pragma unroll
  for (int j = 0; j < 4; ++j) c4[j] = 0.f;

  ull pr[4], prn[4];
  {
    const int t0 = dir ? 255 : 0;
    const u16* pb = pre + (long long)(t0 * 64 + bb) * 2048 + u0 + t8 * 4;
#pragma unroll
    for (int g2 = 0; g2 < 4; ++g2) pr[g2] = *(const ulla*)(pb + g2 * 512);
  }

  for (int tt = 0; tt < 256; ++tt) {
    const int t = dir ? (255 - tt) : tt;

    // ---- stage h_{t-1}: fully coalesced (per-wave 1KB contiguous per b128) ----
    {
      const u16* base;
      if (tt == 0) {
        base = zbuf + dir * 512;
      } else {
        const int tp = dir ? (t + 1) : (t - 1);
        base = o_out + (long long)tp * 65536 + dir * 512;
      }
      const int off = lane * 8;      // u16 offset within 512-wide dir-half
#pragma unroll
      for (int it = 0; it < 8; ++it) {
        const int row = wv + it * 8;
        const float4_ v = *(const float4a*)(base + (long long)row * 1024 + off);
        *(float4a*)((char*)hstage + row * 1024 + ((off * 2) ^ ((row & 7) << 4))) = v;
      }
    }
    __syncthreads();

    // ---- MFMA: acc[ci][bt] over this wave's (gate, K-half) ----
    float4_ acc[2][4];
#pragma unroll
    for (int ci = 0; ci < 2; ++ci)
#pragma unroll
      for (int bt = 0; bt < 4; ++bt) acc[ci][bt] = splat4(0.f);
    const char* hsb = (const char*)hstage;
#pragma unroll
    for (int kc = 0; kc < 8; ++kc) {
      const short8 w0 = __builtin_bit_cast(short8, swf[0][kc]);
      const short8 w1 = __builtin_bit_cast(short8, swf[1][kc]);
#pragma unroll
      for (int bt = 0; bt < 4; ++bt) {
        const int row = bt * 16 + l15;
        const short8 A = *(const short8a*)(hsb + row * 1024 +
                          ((kh * 512 + kc * 64 + q * 16) ^ ((row & 7) << 4)));
        acc[0][bt] = MFMA16(w0, A, acc[0][bt]);
        acc[1][bt] = MFMA16(w1, A, acc[1][bt]);
      }
    }

    // ---- exchange K-half partials: [kh*4+g][b][ (ci*4+q)^(b&7) ] float4 ----
#pragma unroll
    for (int ci = 0; ci < 2; ++ci)
#pragma unroll
      for (int bt = 0; bt < 4; ++bt) {
        const int b = bt * 16 + l15;
        *(float4a*)&xch[(((kh * 4 + g) * 64 + b) * 32) + (((ci * 4 + q) ^ (l15 & 7)) * 4)] = acc[ci][bt];
      }
    __syncthreads();

    // ---- activation: 4 outputs (batch bb, units u0 + t8*4 .. +3) ----
    const int rq = (t8 ^ (bb & 7)) * 4;
    float4_ gv[4];
#pragma unroll
    for (int g2 = 0; g2 < 4; ++g2) {
      const float4_ p0 = *(const float4a*)&xch[((g2 * 64 + bb) * 32) + rq];
      const float4_ p1 = *(const float4a*)&xch[(((4 + g2) * 64 + bb) * 32) + rq];
      gv[g2] = p0 + p1;
    }
    ull hv = 0;
#pragma unroll
    for (int j = 0; j < 4; ++j) {
      const float iv = gv[0][j] + b2f((u16)(pr[0] >> (16 * j)));
      const float fv = gv[1][j] + b2f((u16)(pr[1] >> (16 * j)));
      const float gg = gv[2][j] + b2f((u16)(pr[2] >> (16 * j)));
      const float ov = gv[3][j] + b2f((u16)(pr[3] >> (16 * j)));
      c4[j] = sigm(fv) * c4[j] + sigm(iv) * tanh_(gg);
      const float h = sigm(ov) * tanh_(c4[j]);
      hv |= (ull)f2b(h) << (16 * j);
    }
    // single write-through publish into the ring (= o_out)
    __hip_atomic_store((ull*)(o_out + (long long)(t * 64 + bb) * 1024 + dir * 512 + u0 + t8 * 4), hv,
                       __ATOMIC_RELAXED, __HIP_MEMORY_SCOPE_AGENT);
    asm volatile("s_waitcnt vmcnt(0)" ::: "memory");  // h at coherence point
    __syncthreads();
    if (tid == 0)
      __hip_atomic_store(&myflags[blk * 32], tt + 1, __ATOMIC_RELAXED, __HIP_MEMORY_SCOPE_AGENT);
    // next-step pre prefetch (issues before/during the poll)
    {
      const int ttn = (tt < 255) ? tt + 1 : tt;
      const int tn = dir ? (255 - ttn) : ttn;
      const u16* pb = pre + (long long)(tn * 64 + bb) * 2048 + u0 + t8 * 4;
#pragma unroll
      for (int g2 = 0; g2 < 4; ++g2) prn[g2] = *(const ulla*)(pb + g2 * 512);
    }
    if (tt != 255) {
      // all-wave poll (lanes mirror l15); each wave proceeds to stage on exit
      const int* fp = myflags + l15 * 32;
      int v = __hip_atomic_load(fp, __ATOMIC_RELAXED, __HIP_MEMORY_SCOPE_AGENT);
      while (__all(v >= tt + 1) == 0) {
        __builtin_amdgcn_s_sleep(1);
        v = __hip_atomic_load(fp, __ATOMIC_RELAXED, __HIP_MEMORY_SCOPE_AGENT);
      }
    }
#pragma unroll
    for (int g2 = 0; g2 < 4; ++g2) pr[g2] = prn[g2];
    // keep weight fragments live across the step (discourage remat/sink)
#pragma unroll
    for (int ci = 0; ci < 2; ++ci)
#pragma unroll
      for (int kc = 0; kc < 8; ++kc) asm volatile("" : "+v"(swf[ci][kc]));
  }
}

// ---------------- launcher ----------------
static constexpr long long OFF_WT = 0;
static constexpr long long OFF_BIAS = 19660800;
static constexpr long long OFF_CAT = 19698944;
static constexpr long long OFF_EMB = 36476160;
static constexpr long long OFF_PRE = 44864768;
static constexpr long long OFF_O1 = 179082496;
static constexpr long long OFF_O2 = 212636928;
static constexpr long long OFF_SYNC = 246191360;
static constexpr long long SYNC_BYTES = 16384 + 131072;  // padded flags + zero slot
static constexpr long long OFF_FLAG = OFF_SYNC + SYNC_BYTES;

extern "C" void kernel_launch(void* const* d_in, const int* in_sizes, int n_in,
                              void* d_out, int out_size, void* d_ws, size_t ws_size,
                              hipStream_t stream) {
  char* ws = (char*)d_ws;
  u16* wt = (u16*)(ws + OFF_WT);
  float* biasp = (float*)(ws + OFF_BIAS);
  u16* cat = (u16*)(ws + OFF_CAT);
  u16* emb = (u16*)(ws + OFF_EMB);
  u16* pre0 = (u16*)(ws + OFF_PRE);
  u16* pre1 = pre0 + (long long)16384 * 2048;
  u16* o1 = (u16*)(ws + OFF_O1);
  u16* o2 = (u16*)(ws + OFF_O2);
  int* cnt1 = (int*)(ws + OFF_SYNC);          // 2 dirs x 16 flags x 32-int stride
  int* cnt2 = cnt1 + 1024;
  u16* zbuf = (u16*)(ws + OFF_SYNC + 16384);  // 128KB zero slot
  int* flag = (int*)(ws + OFF_FLAG);

  hipMemsetAsync(ws + OFF_SYNC, 0, SYNC_BYTES, stream);
  k_detect<<<1, 256, 0, stream>>>((const unsigned*)d_in[30], flag);

  WSegs wsg;
  const int widx[14] = {4, 5, 8, 9, 12, 13, 16, 17, 20, 21, 24, 25, 28, 30};
  const int wdst[15] = {0, 32768, 98304, 131072, 196608, 720896, 1769472, 2293760,
                        3342336, 5439488, 6488064, 8585216, 9633792, 9764864, 9816064};
  const int wn[15] = {32768, 65536, 32768, 65536, 524288, 1048576, 524288, 1048576,
                      2097152, 1048576, 2097152, 1048576, 131072, 51200, 14336};
  for (int j = 0; j < 14; ++j) { wsg.src[j] = d_in[widx[j]]; wsg.dst[j] = wdst[j]; wsg.n[j] = wn[j]; }
  wsg.src[14] = nullptr; wsg.dst[14] = wdst[14]; wsg.n[14] = wn[14];
  k_convw<<<1200, 256, 0, stream>>>(wsg, wt, flag);

  BSegs bsg;
  const int ba[8] = {6, 10, 14, 18, 22, 26, 29, 31};
  const int bb[8] = {7, 11, 15, 19, 23, 27, -1, -1};
  const int bdst[8] = {0, 512, 1024, 3072, 5120, 7168, 9216, 9472};
  const int bn_[8] = {512, 512, 2048, 2048, 2048, 2048, 256, 50};
  const int bnp[8] = {512, 512, 2048, 2048, 2048, 2048, 256, 64};
  for (int j = 0; j < 8; ++j) {
    bsg.a[j] = d_in[ba[j]];
    bsg.b[j] = (bb[j] >= 0) ? d_in[bb[j]] : nullptr;
    bsg.dst[j] = bdst[j]; bsg.n[j] = bn_[j]; bsg.np[j] = bnp[j];
  }
  k_convb<<<40, 256, 0, stream>>>(bsg, biasp, flag);

  k_wordgather<<<16384, 128, 0, stream>>>((const int*)d_in[0], d_in[2], cat, flag);
  k_char<<<dim3(256, 2), 256, 0, stream>>>((const int*)d_in[1], d_in[3],
                                           wt + 0, wt + 32768, wt + 98304, wt + 131072,
                                           biasp + 0, biasp + 512, cat, flag);
  k_gemm<64, 64, 1, 0><<<dim3(256, 4), 256, 0, stream>>>(cat, wt + 9633792, biasp + 9216, emb, 256, 512, 256, flag);
  k_gemm<128, 256, 0, 0><<<dim3(128, 8), 256, 0, stream>>>(emb, wt + 196608, biasp + 1024, pre0, 2048, 256, 2048, flag);
  k_gemm<128, 256, 0, 0><<<dim3(128, 8), 256, 0, stream>>>(emb, wt + 1769472, biasp + 3072, pre1, 2048, 256, 2048, flag);
  k_scan<<<dim3(16, 2), 512, 0, stream>>>(pre0, pre1, wt + 720896, wt + 2293760, o1, zbuf, cnt1);
  k_gemm<128, 256, 0, 0><<<dim3(128, 8), 256, 0, stream>>>(o1, wt + 3342336, biasp + 5120, pre0, 2048, 1024, 2048, flag);
  k_gemm<128, 256, 0, 0><<<dim3(128, 8), 256, 0, stream>>>(o1, wt + 6488064, biasp + 7168, pre1, 2048, 1024, 2048, flag);
  k_scan<<<dim3(16, 2), 512, 0, stream>>>(pre0, pre1, wt + 5439488, wt + 8585216, o2, zbuf, cnt2);
  k_gemm<64, 64, 2, 1><<<dim3(256, 1), 256, 0, stream>>>(o2, wt + 9764864, biasp + 9472, d_out, 50, 1024, 50, flag);
}

// Round 11
// 3005.772 us; speedup vs baseline: 3.2494x; 1.1424x over previous
//
// BiLSTM tagger — MI355X. Round 11: 2x CUs for the scan (32 blocks/dir x 16
// units). Post-mortem R10: counters are normalized over 256 CUs; per-ACTIVE-CU
// MFMA ~21%, VALU ~31% -> step is pipe-throughput-bound on 32 CUs, not pure
// latency. Halve per-CU work: wave=(kh,bt) computes ALL 4 gates (A-fragment
// reuse 4x, A-reads 256->64/block); weights 128 VGPR/lane; xch 16KB asymmetric
// (kh1 writes partials, kh0 sums+activates+publishes). Sync = R10's proven
// ring+flags, 32 flags/dir.
#include <hip/hip_runtime.h>

typedef unsigned short u16;
typedef unsigned long long ull;
typedef short short8 __attribute__((ext_vector_type(8)));
typedef float float4_ __attribute__((ext_vector_type(4)));
typedef short8 short8a __attribute__((may_alias));
typedef float4_ float4a __attribute__((may_alias));
typedef ull ulla __attribute__((may_alias));

#define MFMA16(a, b, c) __builtin_amdgcn_mfma_f32_16x16x32_bf16((a), (b), (c), 0, 0, 0)

static __device__ __forceinline__ float b2f(u16 v) { return __uint_as_float(((unsigned)v) << 16); }
static __device__ __forceinline__ u16 f2b(float f) {
  unsigned x = __float_as_uint(f);
  return (u16)((x + 0x7fffu + ((x >> 16) & 1u)) >> 16);
}
static __device__ __forceinline__ float ldv(const void* p, long long i, int isbf) {
  return isbf ? b2f(((const u16*)p)[i]) : ((const float*)p)[i];
}
static __device__ __forceinline__ float sigm(float x) { return 1.f / (1.f + __expf(-x)); }
static __device__ __forceinline__ float tanh_(float x) { return 1.f - 2.f / (__expf(2.f * x) + 1.f); }
static __device__ __forceinline__ float4_ splat4(float v) { float4_ r; r[0]=v; r[1]=v; r[2]=v; r[3]=v; return r; }

// ---------------- dtype detection (f32 vs bf16 input buffers) ----------------
__global__ __launch_bounds__(256) void k_detect(const unsigned* __restrict__ wtag, int* __restrict__ flag) {
  __shared__ int cs;
  if (threadIdx.x == 0) cs = 0;
  __syncthreads();
  int hits = 0;
  for (int i = threadIdx.x; i < 1024; i += 256) {
    unsigned b = (wtag[i] >> 8) & 0x7fu;
    hits += (b >= 0x36u && b <= 0x3fu) ? 1 : 0;
  }
  atomicAdd(&cs, hits);
  __syncthreads();
  if (threadIdx.x == 0) *flag = (cs > 512) ? 1 : 0;
}

// ---------------- weight conversion to bf16 workspace (x8 vectorized) ----------------
struct WSegs { const void* src[15]; int dst[15]; int n[15]; };
__global__ __launch_bounds__(256) void k_convw(WSegs s, u16* __restrict__ wt, const int* __restrict__ flagp) {
  const int isbf = *flagp;
  const long long total8 = 9830400 / 8;
  for (long long i8 = (long long)blockIdx.x * 256 + threadIdx.x; i8 < total8; i8 += (long long)gridDim.x * 256) {
    const long long i = i8 * 8;
    int k = 0;
#pragma unroll
    for (int j = 1; j < 15; ++j) if (i >= (long long)s.dst[j]) k = j;
    const long long loc = i - s.dst[k];
    short8 out;
    if (!s.src[k]) {
      for (int j = 0; j < 8; ++j) out[j] = 0;
    } else if (isbf) {
      out = *(const short8a*)((const u16*)s.src[k] + loc);
    } else {
      const float* fp = (const float*)s.src[k] + loc;
      const float4_ f0 = *(const float4a*)fp;
      const float4_ f1 = *(const float4a*)(fp + 4);
#pragma unroll
      for (int j = 0; j < 4; ++j) { out[j] = (short)f2b(f0[j]); out[j + 4] = (short)f2b(f1[j]); }
    }
    *(short8a*)(wt + i) = out;
  }
}

struct BSegs { const void* a[8]; const void* b[8]; int dst[8]; int n[8]; int np[8]; };
__global__ __launch_bounds__(256) void k_convb(BSegs s, float* __restrict__ bias, const int* __restrict__ flagp) {
  const int isbf = *flagp;
  for (int i = blockIdx.x * 256 + threadIdx.x; i < 9536; i += gridDim.x * 256) {
    int k = 0;
#pragma unroll
    for (int j = 1; j < 8; ++j) if (i >= s.dst[j]) k = j;
    const int loc = i - s.dst[k];
    float v = 0.f;
    if (loc < s.n[k]) {
      v = ldv(s.a[k], loc, isbf);
      if (s.b[k]) v += ldv(s.b[k], loc, isbf);
    }
    bias[i] = v;
  }
}

// ---------------- word embedding gather into cat[:,0:256] ----------------
__global__ __launch_bounds__(128) void k_wordgather(const int* __restrict__ sent, const void* __restrict__ wemb,
                                                    u16* __restrict__ cat, const int* __restrict__ flagp) {
  const int n = blockIdx.x;
  const int idx = sent[n];
  const int isbf = *flagp;
  for (int d = threadIdx.x; d < 256; d += 128)
    cat[(long long)n * 512 + d] = f2b(ldv(wemb, (long long)idx * 256 + d, isbf));
}

// ---------------- char biLSTM: 64 seqs/block, 16 steps, D=64 H=128 ----------------
__global__ __launch_bounds__(256) void k_char(const int* __restrict__ cs, const void* __restrict__ wchar,
                                              const u16* __restrict__ wihF, const u16* __restrict__ whhF,
                                              const u16* __restrict__ wihB, const u16* __restrict__ whhB,
                                              const float* __restrict__ biasF, const float* __restrict__ biasB,
                                              u16* __restrict__ cat, const int* __restrict__ flagp) {
  const int dir = blockIdx.y;
  const int nb = blockIdx.x;
  const u16* wih = dir ? wihB : wihF;
  const u16* whh = dir ? whhB : whhF;
  const float* bias = dir ? biasB : biasF;
  const int isbf = *flagp;
  __shared__ __align__(16) u16 xs[64][72];
  __shared__ __align__(16) u16 hs[64][136];
  const int tid = threadIdx.x, wv = tid >> 6, lane = tid & 63;
  for (int i = tid; i < 64 * 136; i += 256) ((u16*)hs)[i] = 0;
  float c[2][4][4];
#pragma unroll
  for (int a1 = 0; a1 < 2; ++a1)
#pragma unroll
    for (int a2 = 0; a2 < 4; ++a2)
#pragma unroll
      for (int a3 = 0; a3 < 4; ++a3) c[a1][a2][a3] = 0.f;

  for (int tt = 0; tt < 16; ++tt) {
    const int t = dir ? (15 - tt) : tt;
    {
      const int sid = tid >> 2, part = tid & 3;
      const int n = nb * 64 + sid;
      const int idx = cs[n * 16 + t];
#pragma unroll
      for (int q = 0; q < 16; ++q) {
        const int d2 = part * 16 + q;
        float v = 0.f;
        if (idx != 0) v = ldv(wchar, (long long)idx * 64 + d2, isbf);
        xs[sid][d2] = f2b(v);
      }
    }
    __syncthreads();
    float4_ acc[2][4][4];
#pragma unroll
    for (int ut = 0; ut < 2; ++ut)
#pragma unroll
      for (int g = 0; g < 4; ++g) {
        const float bv = bias[g * 128 + (wv + 4 * ut) * 16 + (lane & 15)];
#pragma unroll
        for (int rt = 0; rt < 4; ++rt) acc[ut][g][rt] = splat4(bv);
      }
#pragma unroll
    for (int kc = 0; kc < 6; ++kc) {
      short8 a[4];
      if (kc < 2) {
#pragma unroll
        for (int rt = 0; rt < 4; ++rt)
          a[rt] = *(const short8a*)&xs[rt * 16 + (lane & 15)][kc * 32 + (lane >> 4) * 8];
      } else {
#pragma unroll
        for (int rt = 0; rt < 4; ++rt)
          a[rt] = *(const short8a*)&hs[rt * 16 + (lane & 15)][(kc - 2) * 32 + (lane >> 4) * 8];
      }
#pragma unroll
      for (int ut = 0; ut < 2; ++ut)
#pragma unroll
        for (int g = 0; g < 4; ++g) {
          const int col = g * 128 + (wv + 4 * ut) * 16 + (lane & 15);
          short8 bfr;
          if (kc < 2) bfr = *(const short8a*)(wih + col * 64 + kc * 32 + (lane >> 4) * 8);
          else        bfr = *(const short8a*)(whh + col * 128 + (kc - 2) * 32 + (lane >> 4) * 8);
#pragma unroll
          for (int rt = 0; rt < 4; ++rt) acc[ut][g][rt] = MFMA16(a[rt], bfr, acc[ut][g][rt]);
        }
    }
    __syncthreads();
#pragma unroll
    for (int ut = 0; ut < 2; ++ut)
#pragma unroll
      for (int rt = 0; rt < 4; ++rt)
#pragma unroll
        for (int r = 0; r < 4; ++r) {
          const float iv = acc[ut][0][rt][r];
          const float fv = acc[ut][1][rt][r];
          const float gv = acc[ut][2][rt][r];
          const float ov = acc[ut][3][rt][r];
          float& cc = c[ut][rt][r];
          cc = sigm(fv) * cc + sigm(iv) * tanh_(gv);
          const float h = sigm(ov) * tanh_(cc);
          const int seq = rt * 16 + (lane >> 4) * 4 + r;
          const int u = (wv + 4 * ut) * 16 + (lane & 15);
          const u16 hv = f2b(h);
          hs[seq][u] = hv;
          if (tt == 15) cat[(long long)(nb * 64 + seq) * 512 + 256 + dir * 128 + u] = hv;
        }
  }
}

// ---------------- generic MFMA GEMM ----------------
template <int TM, int TN, int PERM, int OUTM>
__global__ __launch_bounds__(256) void k_gemm(const u16* __restrict__ A, const u16* __restrict__ Wt,
                                              const float* __restrict__ bias, void* __restrict__ Cout,
                                              const int N, const int K, const int ldc,
                                              const int* __restrict__ flagp) {
  constexpr int RT = TM / 16;
  constexpr int CPW = TN / 64;
  const int bm = blockIdx.x, bn = blockIdx.y;
  const int tid = threadIdx.x, wv = tid >> 6, lane = tid & 63;
  __shared__ __align__(16) u16 As[TM][72];
  float4_ acc[CPW][RT];
#pragma unroll
  for (int ci = 0; ci < CPW; ++ci)
#pragma unroll
    for (int rt = 0; rt < RT; ++rt) acc[ci][rt] = splat4(0.f);
  const int nk = K >> 6;
  for (int kc = 0; kc < nk; ++kc) {
    __syncthreads();
    for (int idx = tid; idx < TM * 4; idx += 256) {
      const int r = idx >> 2, sg = idx & 3;
      const u16* src = A + (long long)(bm * TM + r) * K + kc * 64 + sg * 16;
      *(short8a*)&As[r][sg * 16] = *(const short8a*)src;
      *(short8a*)&As[r][sg * 16 + 8] = *(const short8a*)(src + 8);
    }
    __syncthreads();
#pragma unroll
    for (int kk = 0; kk < 2; ++kk) {
      short8 af[RT];
#pragma unroll
      for (int rt = 0; rt < RT; ++rt)
        af[rt] = *(const short8a*)&As[rt * 16 + (lane & 15)][kk * 32 + (lane >> 4) * 8];
#pragma unroll
      for (int ci = 0; ci < CPW; ++ci) {
        const int ct = wv + ci * 4;
        const short8 bf = *(const short8a*)(Wt + (long long)(bn * TN + ct * 16 + (lane & 15)) * K +
                                            kc * 64 + kk * 32 + (lane >> 4) * 8);
#pragma unroll
        for (int rt = 0; rt < RT; ++rt) acc[ci][rt] = MFMA16(af[rt], bf, acc[ci][rt]);
      }
    }
  }
  const int isbf = (OUTM == 1) ? *flagp : 0;
#pragma unroll
  for (int ci = 0; ci < CPW; ++ci)
#pragma unroll
    for (int rt = 0; rt < RT; ++rt)
#pragma unroll
      for (int r = 0; r < 4; ++r) {
        const int row = bm * TM + rt * 16 + (lane >> 4) * 4 + r;
        const int col = bn * TN + (wv + ci * 4) * 16 + (lane & 15);
        if (col < N) {
          const float v = acc[ci][rt][r] + bias[col];
          long long orow;
          if (PERM == 0) orow = row;
          else if (PERM == 1) orow = (long long)(row & 255) * 64 + (row >> 8);
          else orow = (long long)(row & 63) * 256 + (row >> 6);
          if (OUTM == 0) ((u16*)Cout)[orow * ldc + col] = f2b(v);
          else if (isbf) ((u16*)Cout)[orow * ldc + col] = f2b(v);
          else ((float*)Cout)[orow * ldc + col] = v;
        }
      }
}

// ---------------- persistent LSTM scan (one layer, both dirs) ----------------
// grid (32, 2=dir), 512 threads (8 waves). Block owns 16 units. Wave =
// (kh = wv>>2, bt = wv&3) computes ALL 4 gates for its (K-half, batch-tile):
// A-fragments reused 4x, weights 4g x 8kc = 128 VGPR/lane. kh=1 waves write
// gate partials to 16KB xch; kh=0 waves sum + activate + publish (sc1 u64).
// h ring = o_out; flags 32/dir padded 128B; no cache fences anywhere.
__global__ __launch_bounds__(512, 1) void k_scan(const u16* __restrict__ pre0, const u16* __restrict__ pre1,
                                                 const u16* __restrict__ whh0, const u16* __restrict__ whh1,
                                                 u16* __restrict__ o_out, const u16* __restrict__ zbuf,
                                                 int* __restrict__ flags) {
  const int dir = blockIdx.y, blk = blockIdx.x;
  const u16* __restrict__ pre = dir ? pre1 : pre0;
  const u16* __restrict__ whh = dir ? whh1 : whh0;
  int* myflags = flags + dir * 1024;  // 32 flags, 32-int (128B) stride
  const int u0 = blk * 16;
  __shared__ __align__(16) u16 hstage[64 * 512];   // 64KB, XOR-swizzled rows
  __shared__ __align__(16) float xch[4][64][16];   // 16KB gate partials (kh=1)
  const int tid = threadIdx.x, lane = tid & 63;
  const int wv = tid >> 6;
  const int l15 = lane & 15, q = lane >> 4;
  const int kh = wv >> 2, bt = wv & 3;
  const int b = bt * 16 + l15;        // batch this thread's fragment covers

  // weights: 4 gates x 8 kc fragments (rows g*512+u0+l15, k = kh*256+kc*32+q*8)
  float4_ swf[4][8];
#pragma unroll
  for (int g = 0; g < 4; ++g)
#pragma unroll
    for (int kc = 0; kc < 8; ++kc)
      swf[g][kc] = *(const float4a*)(whh + (long long)(g * 512 + u0 + l15) * 512 +
                                     kh * 256 + kc * 32 + q * 8);

  float c4[4];
#pragma unroll
  for (int j = 0; j < 4; ++j) c4[j] = 0.f;

  ull pr[4], prn[4];
  if (kh == 0) {
    const int t0 = dir ? 255 : 0;
    const u16* pb = pre + (long long)(t0 * 64 + b) * 2048 + u0 + q * 4;
#pragma unroll
    for (int g = 0; g < 4; ++g) pr[g] = *(const ulla*)(pb + g * 512);
  }

  for (int tt = 0; tt < 256; ++tt) {
    const int t = dir ? (255 - tt) : tt;

    // ---- stage h_{t-1}: coalesced (per-wave 1KB contiguous per b128) ----
    {
      const u16* base;
      if (tt == 0) {
        base = zbuf + dir * 512;
      } else {
        const int tp = dir ? (t + 1) : (t - 1);
        base = o_out + (long long)tp * 65536 + dir * 512;
      }
      const int off = lane * 8;
#pragma unroll
      for (int it = 0; it < 8; ++it) {
        const int row = wv + it * 8;
        const float4_ v = *(const float4a*)(base + (long long)row * 1024 + off);
        *(float4a*)((char*)hstage + row * 1024 + ((off * 2) ^ ((row & 7) << 4))) = v;
      }
    }
    __syncthreads();

    // ---- MFMA: 4 gates, one A-read per kc (reused 4x) ----
    float4_ acc[4];
#pragma unroll
    for (int g = 0; g < 4; ++g) acc[g] = splat4(0.f);
    const char* hsb = (const char*)hstage;
#pragma unroll
    for (int kc = 0; kc < 8; ++kc) {
      const int row = b;
      const short8 A = *(const short8a*)(hsb + row * 1024 +
                        ((kh * 512 + kc * 64 + q * 16) ^ ((row & 7) << 4)));
      acc[0] = MFMA16(__builtin_bit_cast(short8, swf[0][kc]), A, acc[0]);
      acc[1] = MFMA16(__builtin_bit_cast(short8, swf[1][kc]), A, acc[1]);
      acc[2] = MFMA16(__builtin_bit_cast(short8, swf[2][kc]), A, acc[2]);
      acc[3] = MFMA16(__builtin_bit_cast(short8, swf[3][kc]), A, acc[3]);
    }

    // ---- exchange: kh=1 writes partials; kh=0 sums + activates + publishes ----
    if (kh == 1) {
#pragma unroll
      for (int g = 0; g < 4; ++g)
        *(float4a*)&xch[g][b][(q ^ (l15 & 3)) * 4] = acc[g];
    }
    __syncthreads();
    if (kh == 0) {
#pragma unroll
      for (int g = 0; g < 4; ++g)
        acc[g] += *(const float4a*)&xch[g][b][(q ^ (l15 & 3)) * 4];
      ull hv = 0;
#pragma unroll
      for (int j = 0; j < 4; ++j) {
        const float iv = acc[0][j] + b2f((u16)(pr[0] >> (16 * j)));
        const float fv = acc[1][j] + b2f((u16)(pr[1] >> (16 * j)));
        const float gg = acc[2][j] + b2f((u16)(pr[2] >> (16 * j)));
        const float ov = acc[3][j] + b2f((u16)(pr[3] >> (16 * j)));
        c4[j] = sigm(fv) * c4[j] + sigm(iv) * tanh_(gg);
        const float h = sigm(ov) * tanh_(c4[j]);
        hv |= (ull)f2b(h) << (16 * j);
      }
      // single write-through publish into the ring (= o_out)
      __hip_atomic_store((ull*)(o_out + (long long)(t * 64 + b) * 1024 + dir * 512 + u0 + q * 4), hv,
                         __ATOMIC_RELAXED, __HIP_MEMORY_SCOPE_AGENT);
    }
    asm volatile("s_waitcnt vmcnt(0)" ::: "memory");  // h at coherence point
    __syncthreads();
    if (tid == 0)
      __hip_atomic_store(&myflags[blk * 32], tt + 1, __ATOMIC_RELAXED, __HIP_MEMORY_SCOPE_AGENT);
    // next-step pre prefetch (kh=0 only; overlaps the poll)
    if (kh == 0) {
      const int ttn = (tt < 255) ? tt + 1 : tt;
      const int tn = dir ? (255 - ttn) : ttn;
      const u16* pb = pre + (long long)(tn * 64 + b) * 2048 + u0 + q * 4;
#pragma unroll
      for (int g = 0; g < 4; ++g) prn[g] = *(const ulla*)(pb + g * 512);
    }
    if (tt != 255) {
      // all-wave poll: lanes mirror the 32 flags
      const int* fp = myflags + (lane & 31) * 32;
      int v = __hip_atomic_load(fp, __ATOMIC_RELAXED, __HIP_MEMORY_SCOPE_AGENT);
      while (__all(v >= tt + 1) == 0) {
        __builtin_amdgcn_s_sleep(1);
        v = __hip_atomic_load(fp, __ATOMIC_RELAXED, __HIP_MEMORY_SCOPE_AGENT);
      }
      asm volatile("" ::: "memory");  // forbid hoisting stage loads above poll
    }
    if (kh == 0) {
#pragma unroll
      for (int g = 0; g < 4; ++g) pr[g] = prn[g];
    }
    // keep weight fragments live across the step (discourage remat/sink)
#pragma unroll
    for (int g = 0; g < 4; ++g)
#pragma unroll
      for (int kc = 0; kc < 8; ++kc) asm volatile("" : "+v"(swf[g][kc]));
  }
}

// ---------------- launcher ----------------
static constexpr long long OFF_WT = 0;
static constexpr long long OFF_BIAS = 19660800;
static constexpr long long OFF_CAT = 19698944;
static constexpr long long OFF_EMB = 36476160;
static constexpr long long OFF_PRE = 44864768;
static constexpr long long OFF_O1 = 179082496;
static constexpr long long OFF_O2 = 212636928;
static constexpr long long OFF_SYNC = 246191360;
static constexpr long long SYNC_BYTES = 16384 + 131072;  // padded flags + zero slot
static constexpr long long OFF_FLAG = OFF_SYNC + SYNC_BYTES;

extern "C" void kernel_launch(void* const* d_in, const int* in_sizes, int n_in,
                              void* d_out, int out_size, void* d_ws, size_t ws_size,
                              hipStream_t stream) {
  char* ws = (char*)d_ws;
  u16* wt = (u16*)(ws + OFF_WT);
  float* biasp = (float*)(ws + OFF_BIAS);
  u16* cat = (u16*)(ws + OFF_CAT);
  u16* emb = (u16*)(ws + OFF_EMB);
  u16* pre0 = (u16*)(ws + OFF_PRE);
  u16* pre1 = pre0 + (long long)16384 * 2048;
  u16* o1 = (u16*)(ws + OFF_O1);
  u16* o2 = (u16*)(ws + OFF_O2);
  int* cnt1 = (int*)(ws + OFF_SYNC);          // 2 dirs x 32 flags x 32-int stride
  int* cnt2 = cnt1 + 2048;
  u16* zbuf = (u16*)(ws + OFF_SYNC + 16384);  // 128KB zero slot
  int* flag = (int*)(ws + OFF_FLAG);

  hipMemsetAsync(ws + OFF_SYNC, 0, SYNC_BYTES, stream);
  k_detect<<<1, 256, 0, stream>>>((const unsigned*)d_in[30], flag);

  WSegs wsg;
  const int widx[14] = {4, 5, 8, 9, 12, 13, 16, 17, 20, 21, 24, 25, 28, 30};
  const int wdst[15] = {0, 32768, 98304, 131072, 196608, 720896, 1769472, 2293760,
                        3342336, 5439488, 6488064, 8585216, 9633792, 9764864, 9816064};
  const int wn[15] = {32768, 65536, 32768, 65536, 524288, 1048576, 524288, 1048576,
                      2097152, 1048576, 2097152, 1048576, 131072, 51200, 14336};
  for (int j = 0; j < 14; ++j) { wsg.src[j] = d_in[widx[j]]; wsg.dst[j] = wdst[j]; wsg.n[j] = wn[j]; }
  wsg.src[14] = nullptr; wsg.dst[14] = wdst[14]; wsg.n[14] = wn[14];
  k_convw<<<1200, 256, 0, stream>>>(wsg, wt, flag);

  BSegs bsg;
  const int ba[8] = {6, 10, 14, 18, 22, 26, 29, 31};
  const int bb[8] = {7, 11, 15, 19, 23, 27, -1, -1};
  const int bdst[8] = {0, 512, 1024, 3072, 5120, 7168, 9216, 9472};
  const int bn_[8] = {512, 512, 2048, 2048, 2048, 2048, 256, 50};
  const int bnp[8] = {512, 512, 2048, 2048, 2048, 2048, 256, 64};
  for (int j = 0; j < 8; ++j) {
    bsg.a[j] = d_in[ba[j]];
    bsg.b[j] = (bb[j] >= 0) ? d_in[bb[j]] : nullptr;
    bsg.dst[j] = bdst[j]; bsg.n[j] = bn_[j]; bsg.np[j] = bnp[j];
  }
  k_convb<<<40, 256, 0, stream>>>(bsg, biasp, flag);

  k_wordgather<<<16384, 128, 0, stream>>>((const int*)d_in[0], d_in[2], cat, flag);
  k_char<<<dim3(256, 2), 256, 0, stream>>>((const int*)d_in[1], d_in[3],
                                           wt + 0, wt + 32768, wt + 98304, wt + 131072,
                                           biasp + 0, biasp + 512, cat, flag);
  k_gemm<64, 64, 1, 0><<<dim3(256, 4), 256, 0, stream>>>(cat, wt + 9633792, biasp + 9216, emb, 256, 512, 256, flag);
  k_gemm<128, 256, 0, 0><<<dim3(128, 8), 256, 0, stream>>>(emb, wt + 196608, biasp + 1024, pre0, 2048, 256, 2048, flag);
  k_gemm<128, 256, 0, 0><<<dim3(128, 8), 256, 0, stream>>>(emb, wt + 1769472, biasp + 3072, pre1, 2048, 256, 2048, flag);
  k_scan<<<dim3(32, 2), 512, 0, stream>>>(pre0, pre1, wt + 720896, wt + 2293760, o1, zbuf, cnt1);
  k_gemm<128, 256, 0, 0><<<dim3(128, 8), 256, 0, stream>>>(o1, wt + 3342336, biasp + 5120, pre0, 2048, 1024, 2048, flag);
  k_gemm<128, 256, 0, 0><<<dim3(128, 8), 256, 0, stream>>>(o1, wt + 6488064, biasp + 7168, pre1, 2048, 1024, 2048, flag);
  k_scan<<<dim3(32, 2), 512, 0, stream>>>(pre0, pre1, wt + 5439488, wt + 8585216, o2, zbuf, cnt2);
  k_gemm<64, 64, 2, 1><<<dim3(256, 1), 256, 0, stream>>>(o2, wt + 9764864, biasp + 9472, d_out, 50, 1024, 50, flag);
}

// Round 12
// 2823.393 us; speedup vs baseline: 3.4592x; 1.0646x over previous
//
// BiLSTM tagger — MI355X. Round 12: m97-pattern GEMMs (global_load_lds).
// Post-mortem R11: scan chain is ~3us/step of publish->poll->stage latency;
// diminishing returns. Budget: 866us non-scan, ~450-500 of it in pre1/pre2
// GEMMs running at ~350 TF (B streamed from global per-MFMA). New k_gemm2 =
// verified m97 structure: 128x128 tile, 4 waves x 4x4 frags, A+B staged via
// __builtin_amdgcn_global_load_lds(16B), 2-barrier K-loop. Scan unchanged.
#include <hip/hip_runtime.h>

typedef unsigned short u16;
typedef unsigned long long ull;
typedef short short8 __attribute__((ext_vector_type(8)));
typedef float float4_ __attribute__((ext_vector_type(4)));
typedef short8 short8a __attribute__((may_alias));
typedef float4_ float4a __attribute__((may_alias));
typedef ull ulla __attribute__((may_alias));

#define MFMA16(a, b, c) __builtin_amdgcn_mfma_f32_16x16x32_bf16((a), (b), (c), 0, 0, 0)

static __device__ __forceinline__ float b2f(u16 v) { return __uint_as_float(((unsigned)v) << 16); }
static __device__ __forceinline__ u16 f2b(float f) {
  unsigned x = __float_as_uint(f);
  return (u16)((x + 0x7fffu + ((x >> 16) & 1u)) >> 16);
}
static __device__ __forceinline__ float ldv(const void* p, long long i, int isbf) {
  return isbf ? b2f(((const u16*)p)[i]) : ((const float*)p)[i];
}
static __device__ __forceinline__ float sigm(float x) { return 1.f / (1.f + __expf(-x)); }
static __device__ __forceinline__ float tanh_(float x) { return 1.f - 2.f / (__expf(2.f * x) + 1.f); }
static __device__ __forceinline__ float4_ splat4(float v) { float4_ r; r[0]=v; r[1]=v; r[2]=v; r[3]=v; return r; }

// async global->LDS, 16B per lane (wave-uniform LDS base + lane*16)
static __device__ __forceinline__ void gload16(const u16* g, u16* l) {
  __builtin_amdgcn_global_load_lds((const __attribute__((address_space(1))) unsigned int*)g,
                                   (__attribute__((address_space(3))) unsigned int*)l, 16, 0, 0);
}

// ---------------- dtype detection (f32 vs bf16 input buffers) ----------------
__global__ __launch_bounds__(256) void k_detect(const unsigned* __restrict__ wtag, int* __restrict__ flag) {
  __shared__ int cs;
  if (threadIdx.x == 0) cs = 0;
  __syncthreads();
  int hits = 0;
  for (int i = threadIdx.x; i < 1024; i += 256) {
    unsigned b = (wtag[i] >> 8) & 0x7fu;
    hits += (b >= 0x36u && b <= 0x3fu) ? 1 : 0;
  }
  atomicAdd(&cs, hits);
  __syncthreads();
  if (threadIdx.x == 0) *flag = (cs > 512) ? 1 : 0;
}

// ---------------- weight conversion to bf16 workspace (x8 vectorized) ----------------
struct WSegs { const void* src[15]; int dst[15]; int n[15]; };
__global__ __launch_bounds__(256) void k_convw(WSegs s, u16* __restrict__ wt, const int* __restrict__ flagp) {
  const int isbf = *flagp;
  const long long total8 = 9830400 / 8;
  for (long long i8 = (long long)blockIdx.x * 256 + threadIdx.x; i8 < total8; i8 += (long long)gridDim.x * 256) {
    const long long i = i8 * 8;
    int k = 0;
#pragma unroll
    for (int j = 1; j < 15; ++j) if (i >= (long long)s.dst[j]) k = j;
    const long long loc = i - s.dst[k];
    short8 out;
    if (!s.src[k]) {
      for (int j = 0; j < 8; ++j) out[j] = 0;
    } else if (isbf) {
      out = *(const short8a*)((const u16*)s.src[k] + loc);
    } else {
      const float* fp = (const float*)s.src[k] + loc;
      const float4_ f0 = *(const float4a*)fp;
      const float4_ f1 = *(const float4a*)(fp + 4);
#pragma unroll
      for (int j = 0; j < 4; ++j) { out[j] = (short)f2b(f0[j]); out[j + 4] = (short)f2b(f1[j]); }
    }
    *(short8a*)(wt + i) = out;
  }
}

struct BSegs { const void* a[8]; const void* b[8]; int dst[8]; int n[8]; int np[8]; };
__global__ __launch_bounds__(256) void k_convb(BSegs s, float* __restrict__ bias, const int* __restrict__ flagp) {
  const int isbf = *flagp;
  for (int i = blockIdx.x * 256 + threadIdx.x; i < 9536; i += gridDim.x * 256) {
    int k = 0;
#pragma unroll
    for (int j = 1; j < 8; ++j) if (i >= s.dst[j]) k = j;
    const int loc = i - s.dst[k];
    float v = 0.f;
    if (loc < s.n[k]) {
      v = ldv(s.a[k], loc, isbf);
      if (s.b[k]) v += ldv(s.b[k], loc, isbf);
    }
    bias[i] = v;
  }
}

// ---------------- word embedding gather into cat[:,0:256] ----------------
__global__ __launch_bounds__(128) void k_wordgather(const int* __restrict__ sent, const void* __restrict__ wemb,
                                                    u16* __restrict__ cat, const int* __restrict__ flagp) {
  const int n = blockIdx.x;
  const int idx = sent[n];
  const int isbf = *flagp;
  for (int d = threadIdx.x; d < 256; d += 128)
    cat[(long long)n * 512 + d] = f2b(ldv(wemb, (long long)idx * 256 + d, isbf));
}

// ---------------- char biLSTM: 64 seqs/block, 16 steps, D=64 H=128 ----------------
__global__ __launch_bounds__(256) void k_char(const int* __restrict__ cs, const void* __restrict__ wchar,
                                              const u16* __restrict__ wihF, const u16* __restrict__ whhF,
                                              const u16* __restrict__ wihB, const u16* __restrict__ whhB,
                                              const float* __restrict__ biasF, const float* __restrict__ biasB,
                                              u16* __restrict__ cat, const int* __restrict__ flagp) {
  const int dir = blockIdx.y;
  const int nb = blockIdx.x;
  const u16* wih = dir ? wihB : wihF;
  const u16* whh = dir ? whhB : whhF;
  const float* bias = dir ? biasB : biasF;
  const int isbf = *flagp;
  __shared__ __align__(16) u16 xs[64][72];
  __shared__ __align__(16) u16 hs[64][136];
  const int tid = threadIdx.x, wv = tid >> 6, lane = tid & 63;
  for (int i = tid; i < 64 * 136; i += 256) ((u16*)hs)[i] = 0;
  float c[2][4][4];
#pragma unroll
  for (int a1 = 0; a1 < 2; ++a1)
#pragma unroll
    for (int a2 = 0; a2 < 4; ++a2)
#pragma unroll
      for (int a3 = 0; a3 < 4; ++a3) c[a1][a2][a3] = 0.f;

  for (int tt = 0; tt < 16; ++tt) {
    const int t = dir ? (15 - tt) : tt;
    {
      const int sid = tid >> 2, part = tid & 3;
      const int n = nb * 64 + sid;
      const int idx = cs[n * 16 + t];
#pragma unroll
      for (int q = 0; q < 16; ++q) {
        const int d2 = part * 16 + q;
        float v = 0.f;
        if (idx != 0) v = ldv(wchar, (long long)idx * 64 + d2, isbf);
        xs[sid][d2] = f2b(v);
      }
    }
    __syncthreads();
    float4_ acc[2][4][4];
#pragma unroll
    for (int ut = 0; ut < 2; ++ut)
#pragma unroll
      for (int g = 0; g < 4; ++g) {
        const float bv = bias[g * 128 + (wv + 4 * ut) * 16 + (lane & 15)];
#pragma unroll
        for (int rt = 0; rt < 4; ++rt) acc[ut][g][rt] = splat4(bv);
      }
#pragma unroll
    for (int kc = 0; kc < 6; ++kc) {
      short8 a[4];
      if (kc < 2) {
#pragma unroll
        for (int rt = 0; rt < 4; ++rt)
          a[rt] = *(const short8a*)&xs[rt * 16 + (lane & 15)][kc * 32 + (lane >> 4) * 8];
      } else {
#pragma unroll
        for (int rt = 0; rt < 4; ++rt)
          a[rt] = *(const short8a*)&hs[rt * 16 + (lane & 15)][(kc - 2) * 32 + (lane >> 4) * 8];
      }
#pragma unroll
      for (int ut = 0; ut < 2; ++ut)
#pragma unroll
        for (int g = 0; g < 4; ++g) {
          const int col = g * 128 + (wv + 4 * ut) * 16 + (lane & 15);
          short8 bfr;
          if (kc < 2) bfr = *(const short8a*)(wih + col * 64 + kc * 32 + (lane >> 4) * 8);
          else        bfr = *(const short8a*)(whh + col * 128 + (kc - 2) * 32 + (lane >> 4) * 8);
#pragma unroll
          for (int rt = 0; rt < 4; ++rt) acc[ut][g][rt] = MFMA16(a[rt], bfr, acc[ut][g][rt]);
        }
    }
    __syncthreads();
#pragma unroll
    for (int ut = 0; ut < 2; ++ut)
#pragma unroll
      for (int rt = 0; rt < 4; ++rt)
#pragma unroll
        for (int r = 0; r < 4; ++r) {
          const float iv = acc[ut][0][rt][r];
          const float fv = acc[ut][1][rt][r];
          const float gv = acc[ut][2][rt][r];
          const float ov = acc[ut][3][rt][r];
          float& cc = c[ut][rt][r];
          cc = sigm(fv) * cc + sigm(iv) * tanh_(gv);
          const float h = sigm(ov) * tanh_(cc);
          const int seq = rt * 16 + (lane >> 4) * 4 + r;
          const int u = (wv + 4 * ut) * 16 + (lane & 15);
          const u16 hv = f2b(h);
          hs[seq][u] = hv;
          if (tt == 15) cat[(long long)(nb * 64 + seq) * 512 + 256 + dir * 128 + u] = hv;
        }
  }
}

// ---------------- m97-pattern MFMA GEMM: 128x128 tile, gload_lds staging ----------------
// C[r,j] = A[r,:]*W[j,:] + bias[j]; PERM as before (0 none, 1 embeds remap).
template <int PERM, int OUTM>
__global__ __launch_bounds__(256) void k_gemm2(const u16* __restrict__ A, const u16* __restrict__ Wt,
                                               const float* __restrict__ bias, void* __restrict__ Cout,
                                               const int N, const int K, const int ldc,
                                               const int* __restrict__ flagp) {
  __shared__ __align__(16) u16 As[128 * 64];
  __shared__ __align__(16) u16 Bs[128 * 64];
  const int bm = blockIdx.x, bn = blockIdx.y;
  const int tid = threadIdx.x, wv = tid >> 6, lane = tid & 63;
  const int l15 = lane & 15, q = lane >> 4;
  const int wr = wv >> 1, wc = wv & 1;
  const int srow = tid >> 3, sseg = tid & 7;  // staging: 32 rows/pass, 8x16B segs
  float4_ acc[4][4];
#pragma unroll
  for (int mt = 0; mt < 4; ++mt)
#pragma unroll
    for (int nt = 0; nt < 4; ++nt) acc[mt][nt] = splat4(0.f);
  const int nk = K >> 6;
  for (int kc = 0; kc < nk; ++kc) {
    __syncthreads();  // previous tile's LDS reads complete
#pragma unroll
    for (int j = 0; j < 4; ++j) {
      const int row = srow + j * 32;
      gload16(A + (long long)(bm * 128 + row) * K + kc * 64 + sseg * 8, &As[row * 64 + sseg * 8]);
      gload16(Wt + (long long)(bn * 128 + row) * K + kc * 64 + sseg * 8, &Bs[row * 64 + sseg * 8]);
    }
    asm volatile("s_waitcnt vmcnt(0)" ::: "memory");
    __syncthreads();  // tile staged
#pragma unroll
    for (int kk = 0; kk < 2; ++kk) {
      short8 af[4], bf[4];
#pragma unroll
      for (int mt = 0; mt < 4; ++mt)
        af[mt] = *(const short8a*)&As[(wr * 64 + mt * 16 + l15) * 64 + kk * 32 + q * 8];
#pragma unroll
      for (int nt = 0; nt < 4; ++nt)
        bf[nt] = *(const short8a*)&Bs[(wc * 64 + nt * 16 + l15) * 64 + kk * 32 + q * 8];
#pragma unroll
      for (int mt = 0; mt < 4; ++mt)
#pragma unroll
        for (int nt = 0; nt < 4; ++nt)
          acc[mt][nt] = MFMA16(af[mt], bf[nt], acc[mt][nt]);
    }
  }
  const int isbf = (OUTM == 1) ? *flagp : 0;
#pragma unroll
  for (int mt = 0; mt < 4; ++mt)
#pragma unroll
    for (int nt = 0; nt < 4; ++nt)
#pragma unroll
      for (int r = 0; r < 4; ++r) {
        const int row = bm * 128 + wr * 64 + mt * 16 + q * 4 + r;
        const int col = bn * 128 + wc * 64 + nt * 16 + l15;
        if (col < N) {
          const float v = acc[mt][nt][r] + bias[col];
          long long orow;
          if (PERM == 0) orow = row;
          else orow = (long long)(row & 255) * 64 + (row >> 8);
          if (OUTM == 0) ((u16*)Cout)[orow * ldc + col] = f2b(v);
          else if (isbf) ((u16*)Cout)[orow * ldc + col] = f2b(v);
          else ((float*)Cout)[orow * ldc + col] = v;
        }
      }
}

// ---------------- small GEMM (tag projection only) ----------------
template <int TM, int TN, int PERM, int OUTM>
__global__ __launch_bounds__(256) void k_gemm(const u16* __restrict__ A, const u16* __restrict__ Wt,
                                              const float* __restrict__ bias, void* __restrict__ Cout,
                                              const int N, const int K, const int ldc,
                                              const int* __restrict__ flagp) {
  constexpr int RT = TM / 16;
  constexpr int CPW = TN / 64;
  const int bm = blockIdx.x, bn = blockIdx.y;
  const int tid = threadIdx.x, wv = tid >> 6, lane = tid & 63;
  __shared__ __align__(16) u16 As[TM][72];
  float4_ acc[CPW][RT];
#pragma unroll
  for (int ci = 0; ci < CPW; ++ci)
#pragma unroll
    for (int rt = 0; rt < RT; ++rt) acc[ci][rt] = splat4(0.f);
  const int nk = K >> 6;
  for (int kc = 0; kc < nk; ++kc) {
    __syncthreads();
    for (int idx = tid; idx < TM * 4; idx += 256) {
      const int r = idx >> 2, sg = idx & 3;
      const u16* src = A + (long long)(bm * TM + r) * K + kc * 64 + sg * 16;
      *(short8a*)&As[r][sg * 16] = *(const short8a*)src;
      *(short8a*)&As[r][sg * 16 + 8] = *(const short8a*)(src + 8);
    }
    __syncthreads();
#pragma unroll
    for (int kk = 0; kk < 2; ++kk) {
      short8 af[RT];
#pragma unroll
      for (int rt = 0; rt < RT; ++rt)
        af[rt] = *(const short8a*)&As[rt * 16 + (lane & 15)][kk * 32 + (lane >> 4) * 8];
#pragma unroll
      for (int ci = 0; ci < CPW; ++ci) {
        const int ct = wv + ci * 4;
        const short8 bf = *(const short8a*)(Wt + (long long)(bn * TN + ct * 16 + (lane & 15)) * K +
                                            kc * 64 + kk * 32 + (lane >> 4) * 8);
#pragma unroll
        for (int rt = 0; rt < RT; ++rt) acc[ci][rt] = MFMA16(af[rt], bf, acc[ci][rt]);
      }
    }
  }
  const int isbf = (OUTM == 1) ? *flagp : 0;
#pragma unroll
  for (int ci = 0; ci < CPW; ++ci)
#pragma unroll
    for (int rt = 0; rt < RT; ++rt)
#pragma unroll
      for (int r = 0; r < 4; ++r) {
        const int row = bm * TM + rt * 16 + (lane >> 4) * 4 + r;
        const int col = bn * TN + (wv + ci * 4) * 16 + (lane & 15);
        if (col < N) {
          const float v = acc[ci][rt][r] + bias[col];
          long long orow;
          if (PERM == 0) orow = row;
          else if (PERM == 1) orow = (long long)(row & 255) * 64 + (row >> 8);
          else orow = (long long)(row & 63) * 256 + (row >> 6);
          if (OUTM == 0) ((u16*)Cout)[orow * ldc + col] = f2b(v);
          else if (isbf) ((u16*)Cout)[orow * ldc + col] = f2b(v);
          else ((float*)Cout)[orow * ldc + col] = v;
        }
      }
}

// ---------------- persistent LSTM scan (one layer, both dirs) ----------------
// grid (32, 2=dir), 512 threads (8 waves). Block owns 16 units. Wave =
// (kh = wv>>2, bt = wv&3) computes ALL 4 gates for its (K-half, batch-tile).
// h ring = o_out; flags 32/dir padded 128B; no cache fences anywhere.
__global__ __launch_bounds__(512, 1) void k_scan(const u16* __restrict__ pre0, const u16* __restrict__ pre1,
                                                 const u16* __restrict__ whh0, const u16* __restrict__ whh1,
                                                 u16* __restrict__ o_out, const u16* __restrict__ zbuf,
                                                 int* __restrict__ flags) {
  const int dir = blockIdx.y, blk = blockIdx.x;
  const u16* __restrict__ pre = dir ? pre1 : pre0;
  const u16* __restrict__ whh = dir ? whh1 : whh0;
  int* myflags = flags + dir * 1024;  // 32 flags, 32-int (128B) stride
  const int u0 = blk * 16;
  __shared__ __align__(16) u16 hstage[64 * 512];   // 64KB, XOR-swizzled rows
  __shared__ __align__(16) float xch[4][64][16];   // 16KB gate partials (kh=1)
  const int tid = threadIdx.x, lane = tid & 63;
  const int wv = tid >> 6;
  const int l15 = lane & 15, q = lane >> 4;
  const int kh = wv >> 2, bt = wv & 3;
  const int b = bt * 16 + l15;        // batch this thread's fragment covers

  // weights: 4 gates x 8 kc fragments (rows g*512+u0+l15, k = kh*256+kc*32+q*8)
  float4_ swf[4][8];
#pragma unroll
  for (int g = 0; g < 4; ++g)
#pragma unroll
    for (int kc = 0; kc < 8; ++kc)
      swf[g][kc] = *(const float4a*)(whh + (long long)(g * 512 + u0 + l15) * 512 +
                                     kh * 256 + kc * 32 + q * 8);

  float c4[4];
#pragma unroll
  for (int j = 0; j < 4; ++j) c4[j] = 0.f;

  ull pr[4], prn[4];
  if (kh == 0) {
    const int t0 = dir ? 255 : 0;
    const u16* pb = pre + (long long)(t0 * 64 + b) * 2048 + u0 + q * 4;
#pragma unroll
    for (int g = 0; g < 4; ++g) pr[g] = *(const ulla*)(pb + g * 512);
  }

  for (int tt = 0; tt < 256; ++tt) {
    const int t = dir ? (255 - tt) : tt;

    // ---- stage h_{t-1}: coalesced (per-wave 1KB contiguous per b128) ----
    {
      const u16* base;
      if (tt == 0) {
        base = zbuf + dir * 512;
      } else {
        const int tp = dir ? (t + 1) : (t - 1);
        base = o_out + (long long)tp * 65536 + dir * 512;
      }
      const int off = lane * 8;
#pragma unroll
      for (int it = 0; it < 8; ++it) {
        const int row = wv + it * 8;
        const float4_ v = *(const float4a*)(base + (long long)row * 1024 + off);
        *(float4a*)((char*)hstage + row * 1024 + ((off * 2) ^ ((row & 7) << 4))) = v;
      }
    }
    __syncthreads();

    // ---- MFMA: 4 gates, one A-read per kc (reused 4x) ----
    float4_ acc[4];
#pragma unroll
    for (int g = 0; g < 4; ++g) acc[g] = splat4(0.f);
    const char* hsb = (const char*)hstage;
#pragma unroll
    for (int kc = 0; kc < 8; ++kc) {
      const int row = b;
      const short8 A = *(const short8a*)(hsb + row * 1024 +
                        ((kh * 512 + kc * 64 + q * 16) ^ ((row & 7) << 4)));
      acc[0] = MFMA16(__builtin_bit_cast(short8, swf[0][kc]), A, acc[0]);
      acc[1] = MFMA16(__builtin_bit_cast(short8, swf[1][kc]), A, acc[1]);
      acc[2] = MFMA16(__builtin_bit_cast(short8, swf[2][kc]), A, acc[2]);
      acc[3] = MFMA16(__builtin_bit_cast(short8, swf[3][kc]), A, acc[3]);
    }

    // ---- exchange: kh=1 writes partials; kh=0 sums + activates + publishes ----
    if (kh == 1) {
#pragma unroll
      for (int g = 0; g < 4; ++g)
        *(float4a*)&xch[g][b][(q ^ (l15 & 3)) * 4] = acc[g];
    }
    __syncthreads();
    if (kh == 0) {
#pragma unroll
      for (int g = 0; g < 4; ++g)
        acc[g] += *(const float4a*)&xch[g][b][(q ^ (l15 & 3)) * 4];
      ull hv = 0;
#pragma unroll
      for (int j = 0; j < 4; ++j) {
        const float iv = acc[0][j] + b2f((u16)(pr[0] >> (16 * j)));
        const float fv = acc[1][j] + b2f((u16)(pr[1] >> (16 * j)));
        const float gg = acc[2][j] + b2f((u16)(pr[2] >> (16 * j)));
        const float ov = acc[3][j] + b2f((u16)(pr[3] >> (16 * j)));
        c4[j] = sigm(fv) * c4[j] + sigm(iv) * tanh_(gg);
        const float h = sigm(ov) * tanh_(c4[j]);
        hv |= (ull)f2b(h) << (16 * j);
      }
      __hip_atomic_store((ull*)(o_out + (long long)(t * 64 + b) * 1024 + dir * 512 + u0 + q * 4), hv,
                         __ATOMIC_RELAXED, __HIP_MEMORY_SCOPE_AGENT);
    }
    asm volatile("s_waitcnt vmcnt(0)" ::: "memory");  // h at coherence point
    __syncthreads();
    if (tid == 0)
      __hip_atomic_store(&myflags[blk * 32], tt + 1, __ATOMIC_RELAXED, __HIP_MEMORY_SCOPE_AGENT);
    if (kh == 0) {
      const int ttn = (tt < 255) ? tt + 1 : tt;
      const int tn = dir ? (255 - ttn) : ttn;
      const u16* pb = pre + (long long)(tn * 64 + b) * 2048 + u0 + q * 4;
#pragma unroll
      for (int g = 0; g < 4; ++g) prn[g] = *(const ulla*)(pb + g * 512);
    }
    if (tt != 255) {
      const int* fp = myflags + (lane & 31) * 32;
      int v = __hip_atomic_load(fp, __ATOMIC_RELAXED, __HIP_MEMORY_SCOPE_AGENT);
      while (__all(v >= tt + 1) == 0) {
        __builtin_amdgcn_s_sleep(1);
        v = __hip_atomic_load(fp, __ATOMIC_RELAXED, __HIP_MEMORY_SCOPE_AGENT);
      }
      asm volatile("" ::: "memory");
    }
    if (kh == 0) {
#pragma unroll
      for (int g = 0; g < 4; ++g) pr[g] = prn[g];
    }
#pragma unroll
    for (int g = 0; g < 4; ++g)
#pragma unroll
      for (int kc = 0; kc < 8; ++kc) asm volatile("" : "+v"(swf[g][kc]));
  }
}

// ---------------- launcher ----------------
static constexpr long long OFF_WT = 0;
static constexpr long long OFF_BIAS = 19660800;
static constexpr long long OFF_CAT = 19698944;
static constexpr long long OFF_EMB = 36476160;
static constexpr long long OFF_PRE = 44864768;
static constexpr long long OFF_O1 = 179082496;
static constexpr long long OFF_O2 = 212636928;
static constexpr long long OFF_SYNC = 246191360;
static constexpr long long SYNC_BYTES = 16384 + 131072;  // padded flags + zero slot
static constexpr long long OFF_FLAG = OFF_SYNC + SYNC_BYTES;

extern "C" void kernel_launch(void* const* d_in, const int* in_sizes, int n_in,
                              void* d_out, int out_size, void* d_ws, size_t ws_size,
                              hipStream_t stream) {
  char* ws = (char*)d_ws;
  u16* wt = (u16*)(ws + OFF_WT);
  float* biasp = (float*)(ws + OFF_BIAS);
  u16* cat = (u16*)(ws + OFF_CAT);
  u16* emb = (u16*)(ws + OFF_EMB);
  u16* pre0 = (u16*)(ws + OFF_PRE);
  u16* pre1 = pre0 + (long long)16384 * 2048;
  u16* o1 = (u16*)(ws + OFF_O1);
  u16* o2 = (u16*)(ws + OFF_O2);
  int* cnt1 = (int*)(ws + OFF_SYNC);          // 2 dirs x 32 flags x 32-int stride
  int* cnt2 = cnt1 + 2048;
  u16* zbuf = (u16*)(ws + OFF_SYNC + 16384);  // 128KB zero slot
  int* flag = (int*)(ws + OFF_FLAG);

  hipMemsetAsync(ws + OFF_SYNC, 0, SYNC_BYTES, stream);
  k_detect<<<1, 256, 0, stream>>>((const unsigned*)d_in[30], flag);

  WSegs wsg;
  const int widx[14] = {4, 5, 8, 9, 12, 13, 16, 17, 20, 21, 24, 25, 28, 30};
  const int wdst[15] = {0, 32768, 98304, 131072, 196608, 720896, 1769472, 2293760,
                        3342336, 5439488, 6488064, 8585216, 9633792, 9764864, 9816064};
  const int wn[15] = {32768, 65536, 32768, 65536, 524288, 1048576, 524288, 1048576,
                      2097152, 1048576, 2097152, 1048576, 131072, 51200, 14336};
  for (int j = 0; j < 14; ++j) { wsg.src[j] = d_in[widx[j]]; wsg.dst[j] = wdst[j]; wsg.n[j] = wn[j]; }
  wsg.src[14] = nullptr; wsg.dst[14] = wdst[14]; wsg.n[14] = wn[14];
  k_convw<<<1200, 256, 0, stream>>>(wsg, wt, flag);

  BSegs bsg;
  const int ba[8] = {6, 10, 14, 18, 22, 26, 29, 31};
  const int bb[8] = {7, 11, 15, 19, 23, 27, -1, -1};
  const int bdst[8] = {0, 512, 1024, 3072, 5120, 7168, 9216, 9472};
  const int bn_[8] = {512, 512, 2048, 2048, 2048, 2048, 256, 50};
  const int bnp[8] = {512, 512, 2048, 2048, 2048, 2048, 256, 64};
  for (int j = 0; j < 8; ++j) {
    bsg.a[j] = d_in[ba[j]];
    bsg.b[j] = (bb[j] >= 0) ? d_in[bb[j]] : nullptr;
    bsg.dst[j] = bdst[j]; bsg.n[j] = bn_[j]; bsg.np[j] = bnp[j];
  }
  k_convb<<<40, 256, 0, stream>>>(bsg, biasp, flag);

  k_wordgather<<<16384, 128, 0, stream>>>((const int*)d_in[0], d_in[2], cat, flag);
  k_char<<<dim3(256, 2), 256, 0, stream>>>((const int*)d_in[1], d_in[3],
                                           wt + 0, wt + 32768, wt + 98304, wt + 131072,
                                           biasp + 0, biasp + 512, cat, flag);
  // embeds: [16384x512]@[512x256] -> PERM=1 remap to [S*64+b, 256]
  k_gemm2<1, 0><<<dim3(128, 2), 256, 0, stream>>>(cat, wt + 9633792, biasp + 9216, emb, 256, 512, 256, flag);
  // layer-1 input gates
  k_gemm2<0, 0><<<dim3(128, 16), 256, 0, stream>>>(emb, wt + 196608, biasp + 1024, pre0, 2048, 256, 2048, flag);
  k_gemm2<0, 0><<<dim3(128, 16), 256, 0, stream>>>(emb, wt + 1769472, biasp + 3072, pre1, 2048, 256, 2048, flag);
  k_scan<<<dim3(32, 2), 512, 0, stream>>>(pre0, pre1, wt + 720896, wt + 2293760, o1, zbuf, cnt1);
  // layer-2 input gates
  k_gemm2<0, 0><<<dim3(128, 16), 256, 0, stream>>>(o1, wt + 3342336, biasp + 5120, pre0, 2048, 1024, 2048, flag);
  k_gemm2<0, 0><<<dim3(128, 16), 256, 0, stream>>>(o1, wt + 6488064, biasp + 7168, pre1, 2048, 1024, 2048, flag);
  k_scan<<<dim3(32, 2), 512, 0, stream>>>(pre0, pre1, wt + 5439488, wt + 8585216, o2, zbuf, cnt2);
  // tag projection, perm to [B,S,50]
  k_gemm<64, 64, 2, 1><<<dim3(256, 1), 256, 0, stream>>>(o2, wt + 9764864, biasp + 9472, d_out, 50, 1024, 50, flag);
}